// Round 6
// baseline (378.981 us; speedup 1.0000x reference)
//
#include <hip/hip_runtime.h>

#define N_NODES 50000
#define NUM_P   20000
#define D_DIM   128
#define ALPHA_  0.2f
#define EPS_    1e-12f
#define NT      16      // nodes per block (50000 = 3125*16, 20000 = 1250*16)

__device__ __forceinline__ float4 f4zero() { return make_float4(0.f, 0.f, 0.f, 0.f); }

__device__ __forceinline__ void fma4(float4& a, const float s, const float4 w) {
    a.x = fmaf(s, w.x, a.x); a.y = fmaf(s, w.y, a.y);
    a.z = fmaf(s, w.z, a.z); a.w = fmaf(s, w.w, a.w);
}

__device__ __forceinline__ float4 leaky4(float4 v) {
    v.x = v.x > 0.f ? v.x : ALPHA_ * v.x;
    v.y = v.y > 0.f ? v.y : ALPHA_ * v.y;
    v.z = v.z > 0.f ? v.z : ALPHA_ * v.z;
    v.w = v.w > 0.f ? v.w : ALPHA_ * v.w;
    return v;
}

__device__ __forceinline__ float sumsq4(const float4 v) {
    return fmaf(v.x, v.x, fmaf(v.y, v.y, fmaf(v.z, v.z, v.w * v.w)));
}

__device__ __forceinline__ void scale4(float4& v, const float s) {
    v.x *= s; v.y *= s; v.z *= s; v.w *= s;
}

// Matvec tail: a0/a1 are y for nodes (n0, n1) cols [cg, cg+4). Leaky + L2 norm
// (32-lane half-wave shuffle reduce; all col-owners of a node sit in one
// half-wave) + float4 store. No LDS, no barriers.
__device__ __forceinline__ void finish_and_store(float4 a0, float4 a1,
                                                 const int n0, const int n1, const int cg,
                                                 float* __restrict__ out0,
                                                 float* __restrict__ out1 /*nullable, rows>=NUM_P*/)
{
    a0 = leaky4(a0); a1 = leaky4(a1);
    float s0 = sumsq4(a0), s1 = sumsq4(a1);
    #pragma unroll
    for (int o = 16; o > 0; o >>= 1) { s0 += __shfl_xor(s0, o); s1 += __shfl_xor(s1, o); }
    scale4(a0, 1.0f / fmaxf(sqrtf(s0), EPS_));
    scale4(a1, 1.0f / fmaxf(sqrtf(s1), EPS_));
    *reinterpret_cast<float4*>(&out0[(size_t)n0 * D_DIM + cg]) = a0;
    *reinterpret_cast<float4*>(&out0[(size_t)n1 * D_DIM + cg]) = a1;
    if (out1 != nullptr) {
        if (n0 >= NUM_P) *reinterpret_cast<float4*>(&out1[(size_t)n0 * D_DIM + cg]) = a0;
        if (n1 >= NUM_P) *reinterpret_cast<float4*>(&out1[(size_t)n1 * D_DIM + cg]) = a1;
    }
}

// ---------------------------------------------------------------------------
// SAGE: out0[node] = l2norm(leaky([x[node] | mean_k x[idx[node,k]]] @ W))
// 16 nodes / 256 threads. Matvec blocking: thread = 4 cols x 2 nodes.
// ---------------------------------------------------------------------------
template<int K, bool SPLIT>
__global__ __launch_bounds__(256)
void sage_v6(const float* __restrict__ srcLow,
             const float* __restrict__ srcHigh,
             const int*   __restrict__ idx,
             const float* __restrict__ W,      // [2D][D] row-major
             float* __restrict__ out0,
             float* __restrict__ out1)
{
    __shared__ float xs[NT][2 * D_DIM];   // [n][0:128]=self, [128:256]=neigh-mean
    __shared__ int   sidx[NT * K];

    const int tid  = threadIdx.x;
    const int base = blockIdx.x * NT;

    for (int i = tid; i < NT * K; i += 256)
        sidx[i] = idx[(size_t)base * K + i];
    __syncthreads();

    // ---- gather: 8 groups of 32 lanes, float4 rows ----
    {
        const int gp = tid >> 5;
        const int l  = tid & 31;
        for (int n = gp; n < NT; n += 8) {
            const int node = base + n;
            const float* sp = (!SPLIT || node < NUM_P) ? srcLow : srcHigh;
            const float4 s4 = reinterpret_cast<const float4*>(sp + (size_t)node * D_DIM)[l];
            float4 a4 = f4zero();
            for (int k = 0; k < K; ++k) {
                const int r = sidx[n * K + k];
                const float* rp = (!SPLIT || r < NUM_P) ? srcLow : srcHigh;
                const float4 v4 = reinterpret_cast<const float4*>(rp + (size_t)r * D_DIM)[l];
                a4.x += v4.x; a4.y += v4.y; a4.z += v4.z; a4.w += v4.w;
            }
            scale4(a4, 1.0f / (float)K);
            reinterpret_cast<float4*>(&xs[n][0])[l]     = s4;
            reinterpret_cast<float4*>(&xs[n][D_DIM])[l] = a4;
        }
    }
    __syncthreads();

    // ---- matvec: thread owns cols [cg,cg+4) for nodes ng, ng+8 ----
    const int cg = (tid & 31) * 4;
    const int ng = tid >> 5;
    float4 a0 = f4zero(), a1 = f4zero();
    for (int c = 0; c < 2 * D_DIM; c += 4) {
        const float4 x0 = *reinterpret_cast<const float4*>(&xs[ng][c]);
        const float4 x1 = *reinterpret_cast<const float4*>(&xs[ng + 8][c]);
        const float4 w0 = *reinterpret_cast<const float4*>(&W[(size_t)(c + 0) * D_DIM + cg]);
        const float4 w1 = *reinterpret_cast<const float4*>(&W[(size_t)(c + 1) * D_DIM + cg]);
        const float4 w2 = *reinterpret_cast<const float4*>(&W[(size_t)(c + 2) * D_DIM + cg]);
        const float4 w3 = *reinterpret_cast<const float4*>(&W[(size_t)(c + 3) * D_DIM + cg]);
        fma4(a0, x0.x, w0); fma4(a0, x0.y, w1); fma4(a0, x0.z, w2); fma4(a0, x0.w, w3);
        fma4(a1, x1.x, w0); fma4(a1, x1.y, w1); fma4(a1, x1.z, w2); fma4(a1, x1.w, w3);
    }

    finish_and_store(a0, a1, base + ng, base + ng + 8, cg, out0, out1);
}

// ---------------------------------------------------------------------------
// Temporal: out[n] = l2norm(leaky([head[n] | ((mean_p hist[p,n]) @ Whis)] @ WT))
// 16 nodes / 256 threads, nodes < NUM_P. hist-mean parked in xs[][128:],
// tf computed into registers then overwritten in place.
// ---------------------------------------------------------------------------
__global__ __launch_bounds__(256)
void temporal_v6(const float* __restrict__ head,   // rows < NUM_P used
                 const float* __restrict__ hist,   // [3][NUM_P][D]
                 const float* __restrict__ Whis,   // [D][D]
                 const float* __restrict__ WT,     // [2D][D]
                 float* __restrict__ outp)
{
    __shared__ float xs[NT][2 * D_DIM];   // [n][0:128]=head, [128:256]=hm -> tf

    const int tid  = threadIdx.x;
    const int base = blockIdx.x * NT;
    const size_t HS = (size_t)NUM_P * D_DIM;

    // ---- phase 1: head + hist mean ----
    {
        const int gp = tid >> 5;
        const int l  = tid & 31;
        for (int n = gp; n < NT; n += 8) {
            const size_t off = (size_t)(base + n) * D_DIM;
            const float4 h4 = reinterpret_cast<const float4*>(head + off)[l];
            const float4 p0 = reinterpret_cast<const float4*>(hist + off)[l];
            const float4 p1 = reinterpret_cast<const float4*>(hist + off + HS)[l];
            const float4 p2 = reinterpret_cast<const float4*>(hist + off + 2 * HS)[l];
            float4 m4;
            m4.x = (p0.x + p1.x + p2.x) * (1.0f / 3.0f);
            m4.y = (p0.y + p1.y + p2.y) * (1.0f / 3.0f);
            m4.z = (p0.z + p1.z + p2.z) * (1.0f / 3.0f);
            m4.w = (p0.w + p1.w + p2.w) * (1.0f / 3.0f);
            reinterpret_cast<float4*>(&xs[n][0])[l]     = h4;
            reinterpret_cast<float4*>(&xs[n][D_DIM])[l] = m4;
        }
    }
    __syncthreads();

    const int cg = (tid & 31) * 4;
    const int ng = tid >> 5;

    // ---- phase 1b: tf = hm @ Whis (K=128) into registers ----
    float4 t0 = f4zero(), t1 = f4zero();
    for (int c = 0; c < D_DIM; c += 4) {
        const float4 x0 = *reinterpret_cast<const float4*>(&xs[ng][D_DIM + c]);
        const float4 x1 = *reinterpret_cast<const float4*>(&xs[ng + 8][D_DIM + c]);
        const float4 w0 = *reinterpret_cast<const float4*>(&Whis[(size_t)(c + 0) * D_DIM + cg]);
        const float4 w1 = *reinterpret_cast<const float4*>(&Whis[(size_t)(c + 1) * D_DIM + cg]);
        const float4 w2 = *reinterpret_cast<const float4*>(&Whis[(size_t)(c + 2) * D_DIM + cg]);
        const float4 w3 = *reinterpret_cast<const float4*>(&Whis[(size_t)(c + 3) * D_DIM + cg]);
        fma4(t0, x0.x, w0); fma4(t0, x0.y, w1); fma4(t0, x0.z, w2); fma4(t0, x0.w, w3);
        fma4(t1, x1.x, w0); fma4(t1, x1.y, w1); fma4(t1, x1.z, w2); fma4(t1, x1.w, w3);
    }
    __syncthreads();   // all hm reads done
    *reinterpret_cast<float4*>(&xs[ng][D_DIM + cg])     = t0;
    *reinterpret_cast<float4*>(&xs[ng + 8][D_DIM + cg]) = t1;
    __syncthreads();

    // ---- phase 2: y = [head | tf] @ WT (K=256) ----
    float4 a0 = f4zero(), a1 = f4zero();
    for (int c = 0; c < 2 * D_DIM; c += 4) {
        const float4 x0 = *reinterpret_cast<const float4*>(&xs[ng][c]);
        const float4 x1 = *reinterpret_cast<const float4*>(&xs[ng + 8][c]);
        const float4 w0 = *reinterpret_cast<const float4*>(&WT[(size_t)(c + 0) * D_DIM + cg]);
        const float4 w1 = *reinterpret_cast<const float4*>(&WT[(size_t)(c + 1) * D_DIM + cg]);
        const float4 w2 = *reinterpret_cast<const float4*>(&WT[(size_t)(c + 2) * D_DIM + cg]);
        const float4 w3 = *reinterpret_cast<const float4*>(&WT[(size_t)(c + 3) * D_DIM + cg]);
        fma4(a0, x0.x, w0); fma4(a0, x0.y, w1); fma4(a0, x0.z, w2); fma4(a0, x0.w, w3);
        fma4(a1, x1.x, w0); fma4(a1, x1.y, w1); fma4(a1, x1.z, w2); fma4(a1, x1.w, w3);
    }

    finish_and_store(a0, a1, base + ng, base + ng + 8, cg, outp, nullptr);
}

// ---------------------------------------------------------------------------
extern "C" void kernel_launch(void* const* d_in, const int* in_sizes, int n_in,
                              void* d_out, int out_size, void* d_ws, size_t ws_size,
                              hipStream_t stream)
{
    (void)in_sizes; (void)n_in; (void)out_size; (void)d_ws; (void)ws_size;

    const float* feats = (const float*)d_in[0];
    const int*   idx1  = (const int*)  d_in[1];
    const int*   idx2  = (const int*)  d_in[2];
    const float* hist1 = (const float*)d_in[3];
    const float* hist2 = (const float*)d_in[4];
    const float* W1    = (const float*)d_in[5];
    const float* W2    = (const float*)d_in[6];
    const float* Whis  = (const float*)d_in[7];
    const float* WT    = (const float*)d_in[8];

    float* out = (float*)d_out;
    float* h1o = out;                                  // h1  [N, D]
    float* h2o = out + (size_t)N_NODES * D_DIM;        // h2  [N, D]
    float* fo  = out + 2 * (size_t)N_NODES * D_DIM;    // feat [N, D]

    const int sage_blocks = N_NODES / NT;  // 3125
    const int temp_blocks = NUM_P   / NT;  // 1250

    // h1 = sage(feats, idx1, W1)
    sage_v6<25, false><<<sage_blocks, 256, 0, stream>>>(feats, feats, idx1, W1, h1o, nullptr);
    // f1 = temporal(h1[:NUM], hist1) -> staged in feat rows [0, NUM)
    temporal_v6<<<temp_blocks, 256, 0, stream>>>(h1o, hist1, Whis, WT, fo);
    // h2 = sage(h1_copy, idx2, W2); rows >= NUM mirrored into feat tail
    // (reads fo rows [0,NUM) and h1o; writes fo rows [NUM,N) — disjoint)
    sage_v6<10, true><<<sage_blocks, 256, 0, stream>>>(fo, h1o, idx2, W2, h2o, fo);
    // f2 = temporal(h2[:NUM], hist2) -> feat rows [0, NUM), overwrites f1
    temporal_v6<<<temp_blocks, 256, 0, stream>>>(h2o, hist2, Whis, WT, fo);
}

// Round 7
// 245.695 us; speedup vs baseline: 1.5425x; 1.5425x over previous
//
#include <hip/hip_runtime.h>
#include <hip/hip_bf16.h>

#define N_NODES 50000
#define NUM_P   20000
#define D_DIM   128
#define ALPHA_  0.2f
#define EPS_    1e-12f
#define NT      16      // nodes per block (50000 = 3125*16, 20000 = 1250*16)

typedef __attribute__((ext_vector_type(8))) short bf16x8;
typedef __attribute__((ext_vector_type(4))) float f32x4;

__device__ __forceinline__ float4 f4zero() { return make_float4(0.f, 0.f, 0.f, 0.f); }

__device__ __forceinline__ void scale4(float4& v, const float s) {
    v.x *= s; v.y *= s; v.z *= s; v.w *= s;
}

__device__ __forceinline__ short f2bf(float f) {
    __hip_bfloat16 h = __float2bfloat16(f);
    return *reinterpret_cast<short*>(&h);
}

__device__ __forceinline__ short4 pack4(const float4 v) {
    short4 s;
    s.x = f2bf(v.x); s.y = f2bf(v.y); s.z = f2bf(v.z); s.w = f2bf(v.w);
    return s;
}

// ---------------------------------------------------------------------------
// Weight pre-transpose+cvt: o[sel][j][c] = bf16(W_sel[c][j]); sel 0->Wa, 1->Wb.
// o is [2][128][256] bf16.
// ---------------------------------------------------------------------------
__global__ __launch_bounds__(256)
void wcvt_kernel(const float* __restrict__ Wa, const float* __restrict__ Wb,
                 short* __restrict__ o)
{
    const int i = blockIdx.x * 256 + threadIdx.x;   // 0..65535
    const float* W = (i < 32768) ? Wa : Wb;
    const int t = i & 32767;
    const int j = t >> 8;        // 0..127 (output col of W = row of W^T)
    const int c = t & 255;       // 0..255 (k)
    o[i] = f2bf(W[(size_t)c * D_DIM + j]);
}

// ---------------------------------------------------------------------------
// MFMA SAGE: out0[node] = l2norm(leaky([x[node] | mean_k x[idx]] @ W))
// 16 nodes / 256 threads (4 waves). A (bf16, XOR-swizzled) in LDS; B = W^T bf16
// from global (WTg[128][256]); 16x16x32 MFMA; wave w owns cols [32w, 32w+32).
// ---------------------------------------------------------------------------
template<int K, bool SPLIT>
__global__ __launch_bounds__(256)
void sage_mfma(const float* __restrict__ srcLow,
               const float* __restrict__ srcHigh,
               const int*   __restrict__ idx,
               const short* __restrict__ WTg,    // [128][256] bf16 = W^T
               float* __restrict__ out0,
               float* __restrict__ out1)
{
    __shared__ __align__(16) short xs[NT * 2 * D_DIM];   // [n][256] bf16, swizzled
    __shared__ float ys[NT * 132];                       // [n][132] padded fp32
    __shared__ float rnorm[NT];
    __shared__ int   sidx[NT * K];

    const int tid  = threadIdx.x;
    const int base = blockIdx.x * NT;

    for (int i = tid; i < NT * K; i += 256)
        sidx[i] = idx[(size_t)base * K + i];
    __syncthreads();

    // ---- gather: 8 groups of 32 lanes; fp32 accumulate, bf16 swizzled store
    {
        const int gp = tid >> 5;
        const int l  = tid & 31;
        for (int n = gp; n < NT; n += 8) {
            const int node = base + n;
            const float* sp = (!SPLIT || node < NUM_P) ? srcLow : srcHigh;
            const float4 s4 = reinterpret_cast<const float4*>(sp + (size_t)node * D_DIM)[l];
            float4 a4 = f4zero();
            for (int k = 0; k < K; ++k) {
                const int r = sidx[n * K + k];
                const float* rp = (!SPLIT || r < NUM_P) ? srcLow : srcHigh;
                const float4 v4 = reinterpret_cast<const float4*>(rp + (size_t)r * D_DIM)[l];
                a4.x += v4.x; a4.y += v4.y; a4.z += v4.z; a4.w += v4.w;
            }
            scale4(a4, 1.0f / (float)K);
            const int swzn = (n & 7) << 3;   // XOR swizzle, short units (16B groups)
            *reinterpret_cast<short4*>(&xs[n * 256 + ((l * 4) ^ swzn)])         = pack4(s4);
            *reinterpret_cast<short4*>(&xs[n * 256 + ((D_DIM + l * 4) ^ swzn)]) = pack4(a4);
        }
    }
    __syncthreads();

    // ---- MFMA: wave w -> cols [32w, 32w+32), two 16-col tiles, K=256 in 8 steps
    const int w    = tid >> 6;
    const int l    = tid & 63;
    const int arow = l & 15;          // A row (node) / B,D col-local
    const int kg   = l >> 4;          // k-group 0..3
    const int swz  = (arow & 7) << 3;

    f32x4 acc0 = {0.f, 0.f, 0.f, 0.f};
    f32x4 acc1 = {0.f, 0.f, 0.f, 0.f};
    const int colbase = w * 32;
    const short* b0 = WTg + (size_t)(colbase + arow) * 256 + kg * 8;
    const short* b1 = b0 + 16 * 256;

    #pragma unroll
    for (int step = 0; step < 8; ++step) {
        const int aoff = arow * 256 + ((step * 32 + kg * 8) ^ swz);
        const bf16x8 av  = *reinterpret_cast<const bf16x8*>(&xs[aoff]);
        const bf16x8 bv0 = *reinterpret_cast<const bf16x8*>(b0 + step * 32);
        const bf16x8 bv1 = *reinterpret_cast<const bf16x8*>(b1 + step * 32);
        acc0 = __builtin_amdgcn_mfma_f32_16x16x32_bf16(av, bv0, acc0, 0, 0, 0);
        acc1 = __builtin_amdgcn_mfma_f32_16x16x32_bf16(av, bv1, acc1, 0, 0, 0);
    }

    // ---- epilogue: leaky -> ys (D layout: row=(l>>4)*4+r, col=l&15)
    {
        const int r0 = kg * 4;
        #pragma unroll
        for (int r = 0; r < 4; ++r) {
            float v0 = acc0[r]; v0 = v0 > 0.f ? v0 : ALPHA_ * v0;
            float v1 = acc1[r]; v1 = v1 > 0.f ? v1 : ALPHA_ * v1;
            ys[(r0 + r) * 132 + colbase + arow]      = v0;
            ys[(r0 + r) * 132 + colbase + 16 + arow] = v1;
        }
    }
    __syncthreads();

    // ---- row norms: 16 lanes per node
    {
        const int n  = tid >> 4;
        const int ll = tid & 15;
        float s = 0.f;
        #pragma unroll
        for (int jj = 0; jj < D_DIM; jj += 16) { const float t = ys[n * 132 + ll + jj]; s += t * t; }
        #pragma unroll
        for (int o = 8; o > 0; o >>= 1) s += __shfl_xor(s, o);
        if (ll == 0) rnorm[n] = 1.0f / fmaxf(sqrtf(s), EPS_);
    }
    __syncthreads();

    // ---- normalize + write
    {
        const int j  = tid & 127;
        const int g  = tid >> 7;
        #pragma unroll
        for (int r = 0; r < 8; ++r) {
            const int n    = g * 8 + r;
            const int node = base + n;
            const float v  = ys[n * 132 + j] * rnorm[n];
            out0[(size_t)node * D_DIM + j] = v;
            if (out1 != nullptr && node >= NUM_P) out1[(size_t)node * D_DIM + j] = v;
        }
    }
}

// ---------------------------------------------------------------------------
// Fallback fp32 SAGE (v5, proven): used when ws_size is too small for WTg.
// ---------------------------------------------------------------------------
template<int K, bool SPLIT>
__global__ __launch_bounds__(256)
void sage_v5(const float* __restrict__ srcLow,
             const float* __restrict__ srcHigh,
             const int*   __restrict__ idx,
             const float* __restrict__ W,
             float* __restrict__ out0,
             float* __restrict__ out1)
{
    __shared__ float xs[NT][2 * D_DIM];
    __shared__ int   sidx[NT * K];
    __shared__ float rnorm[NT];

    const int tid  = threadIdx.x;
    const int base = blockIdx.x * NT;

    for (int i = tid; i < NT * K; i += 256)
        sidx[i] = idx[(size_t)base * K + i];
    __syncthreads();

    {
        const int gp = tid >> 5;
        const int l  = tid & 31;
        for (int n = gp; n < NT; n += 8) {
            const int node = base + n;
            const float* sp = (!SPLIT || node < NUM_P) ? srcLow : srcHigh;
            const float4 s4 = reinterpret_cast<const float4*>(sp + (size_t)node * D_DIM)[l];
            float4 a4 = f4zero();
            for (int k = 0; k < K; ++k) {
                const int r = sidx[n * K + k];
                const float* rp = (!SPLIT || r < NUM_P) ? srcLow : srcHigh;
                const float4 v4 = reinterpret_cast<const float4*>(rp + (size_t)r * D_DIM)[l];
                a4.x += v4.x; a4.y += v4.y; a4.z += v4.z; a4.w += v4.w;
            }
            scale4(a4, 1.0f / (float)K);
            reinterpret_cast<float4*>(&xs[n][0])[l]     = s4;
            reinterpret_cast<float4*>(&xs[n][D_DIM])[l] = a4;
        }
    }
    __syncthreads();

    const int j  = tid & 127;
    const int g  = tid >> 7;
    const int nb = g * 8;

    float acc[8];
    #pragma unroll
    for (int r = 0; r < 8; ++r) acc[r] = 0.f;
    for (int c4 = 0; c4 < (2 * D_DIM) / 4; ++c4) {
        const int c = c4 * 4;
        const float w0 = W[(size_t)(c + 0) * D_DIM + j];
        const float w1 = W[(size_t)(c + 1) * D_DIM + j];
        const float w2 = W[(size_t)(c + 2) * D_DIM + j];
        const float w3 = W[(size_t)(c + 3) * D_DIM + j];
        #pragma unroll
        for (int r = 0; r < 8; ++r) {
            const float4 xv = *reinterpret_cast<const float4*>(&xs[nb + r][c]);
            acc[r] = fmaf(xv.w, w3, fmaf(xv.z, w2, fmaf(xv.y, w1, fmaf(xv.x, w0, acc[r]))));
        }
    }
    __syncthreads();

    #pragma unroll
    for (int r = 0; r < 8; ++r) {
        float v = acc[r];
        v = v > 0.f ? v : ALPHA_ * v;
        xs[nb + r][j] = v;
    }
    __syncthreads();

    {
        const int n  = tid >> 4;
        const int ll = tid & 15;
        float s = 0.f;
        #pragma unroll
        for (int jj = ll; jj < D_DIM; jj += 16) { const float t = xs[n][jj]; s += t * t; }
        #pragma unroll
        for (int o = 8; o > 0; o >>= 1) s += __shfl_xor(s, o);
        if (ll == 0) rnorm[n] = 1.0f / fmaxf(sqrtf(s), EPS_);
    }
    __syncthreads();

    #pragma unroll
    for (int r = 0; r < 8; ++r) {
        const int n    = nb + r;
        const int node = base + n;
        const float v  = xs[n][j] * rnorm[n];
        out0[(size_t)node * D_DIM + j] = v;
        if (out1 != nullptr && node >= NUM_P) out1[(size_t)node * D_DIM + j] = v;
    }
}

// ---------------------------------------------------------------------------
// Temporal (v5, proven): out[n] = l2norm(leaky([head|((mean hist)@Whis)] @ WT))
// ---------------------------------------------------------------------------
__global__ __launch_bounds__(256)
void temporal_v5(const float* __restrict__ head,
                 const float* __restrict__ hist,
                 const float* __restrict__ Whis,
                 const float* __restrict__ WT,
                 float* __restrict__ outp)
{
    __shared__ float xs[NT][2 * D_DIM];
    __shared__ float hm[NT][D_DIM];
    __shared__ float rnorm[NT];

    const int tid  = threadIdx.x;
    const int base = blockIdx.x * NT;
    const size_t HS = (size_t)NUM_P * D_DIM;

    {
        const int gp = tid >> 5;
        const int l  = tid & 31;
        for (int n = gp; n < NT; n += 8) {
            const size_t off = (size_t)(base + n) * D_DIM;
            const float4 h4 = reinterpret_cast<const float4*>(head + off)[l];
            const float4 p0 = reinterpret_cast<const float4*>(hist + off)[l];
            const float4 p1 = reinterpret_cast<const float4*>(hist + off + HS)[l];
            const float4 p2 = reinterpret_cast<const float4*>(hist + off + 2 * HS)[l];
            float4 m4;
            m4.x = (p0.x + p1.x + p2.x) * (1.0f / 3.0f);
            m4.y = (p0.y + p1.y + p2.y) * (1.0f / 3.0f);
            m4.z = (p0.z + p1.z + p2.z) * (1.0f / 3.0f);
            m4.w = (p0.w + p1.w + p2.w) * (1.0f / 3.0f);
            reinterpret_cast<float4*>(&xs[n][0])[l] = h4;
            reinterpret_cast<float4*>(&hm[n][0])[l] = m4;
        }
    }
    __syncthreads();

    const int j  = tid & 127;
    const int g  = tid >> 7;
    const int nb = g * 8;

    {
        float a2[8];
        #pragma unroll
        for (int r = 0; r < 8; ++r) a2[r] = 0.f;
        for (int c4 = 0; c4 < D_DIM / 4; ++c4) {
            const int c = c4 * 4;
            const float w0 = Whis[(size_t)(c + 0) * D_DIM + j];
            const float w1 = Whis[(size_t)(c + 1) * D_DIM + j];
            const float w2 = Whis[(size_t)(c + 2) * D_DIM + j];
            const float w3 = Whis[(size_t)(c + 3) * D_DIM + j];
            #pragma unroll
            for (int r = 0; r < 8; ++r) {
                const float4 xv = *reinterpret_cast<const float4*>(&hm[nb + r][c]);
                a2[r] = fmaf(xv.w, w3, fmaf(xv.z, w2, fmaf(xv.y, w1, fmaf(xv.x, w0, a2[r]))));
            }
        }
        __syncthreads();
        #pragma unroll
        for (int r = 0; r < 8; ++r) xs[nb + r][D_DIM + j] = a2[r];
    }
    __syncthreads();

    float acc[8];
    #pragma unroll
    for (int r = 0; r < 8; ++r) acc[r] = 0.f;
    for (int c4 = 0; c4 < (2 * D_DIM) / 4; ++c4) {
        const int c = c4 * 4;
        const float w0 = WT[(size_t)(c + 0) * D_DIM + j];
        const float w1 = WT[(size_t)(c + 1) * D_DIM + j];
        const float w2 = WT[(size_t)(c + 2) * D_DIM + j];
        const float w3 = WT[(size_t)(c + 3) * D_DIM + j];
        #pragma unroll
        for (int r = 0; r < 8; ++r) {
            const float4 xv = *reinterpret_cast<const float4*>(&xs[nb + r][c]);
            acc[r] = fmaf(xv.w, w3, fmaf(xv.z, w2, fmaf(xv.y, w1, fmaf(xv.x, w0, acc[r]))));
        }
    }
    __syncthreads();

    #pragma unroll
    for (int r = 0; r < 8; ++r) {
        float v = acc[r];
        v = v > 0.f ? v : ALPHA_ * v;
        xs[nb + r][j] = v;
    }
    __syncthreads();

    {
        const int n  = tid >> 4;
        const int ll = tid & 15;
        float s = 0.f;
        #pragma unroll
        for (int jj = ll; jj < D_DIM; jj += 16) { const float t = xs[n][jj]; s += t * t; }
        #pragma unroll
        for (int o = 8; o > 0; o >>= 1) s += __shfl_xor(s, o);
        if (ll == 0) rnorm[n] = 1.0f / fmaxf(sqrtf(s), EPS_);
    }
    __syncthreads();

    #pragma unroll
    for (int r = 0; r < 8; ++r) {
        const int n = nb + r;
        outp[(size_t)(base + n) * D_DIM + j] = xs[n][j] * rnorm[n];
    }
}

// ---------------------------------------------------------------------------
extern "C" void kernel_launch(void* const* d_in, const int* in_sizes, int n_in,
                              void* d_out, int out_size, void* d_ws, size_t ws_size,
                              hipStream_t stream)
{
    (void)in_sizes; (void)n_in; (void)out_size;

    const float* feats = (const float*)d_in[0];
    const int*   idx1  = (const int*)  d_in[1];
    const int*   idx2  = (const int*)  d_in[2];
    const float* hist1 = (const float*)d_in[3];
    const float* hist2 = (const float*)d_in[4];
    const float* W1    = (const float*)d_in[5];
    const float* W2    = (const float*)d_in[6];
    const float* Whis  = (const float*)d_in[7];
    const float* WT    = (const float*)d_in[8];

    float* out = (float*)d_out;
    float* h1o = out;
    float* h2o = out + (size_t)N_NODES * D_DIM;
    float* fo  = out + 2 * (size_t)N_NODES * D_DIM;

    const int sage_blocks = N_NODES / NT;  // 3125
    const int temp_blocks = NUM_P   / NT;  // 1250

    const bool use_mfma = ws_size >= 2u * 32768u * sizeof(short);   // 128 KiB

    if (use_mfma) {
        short* W1Tg = (short*)d_ws;            // [128][256] bf16
        short* W2Tg = W1Tg + 32768;
        wcvt_kernel<<<256, 256, 0, stream>>>(W1, W2, W1Tg);

        sage_mfma<25, false><<<sage_blocks, 256, 0, stream>>>(feats, feats, idx1, W1Tg, h1o, nullptr);
        temporal_v5<<<temp_blocks, 256, 0, stream>>>(h1o, hist1, Whis, WT, fo);
        sage_mfma<10, true><<<sage_blocks, 256, 0, stream>>>(fo, h1o, idx2, W2Tg, h2o, fo);
        temporal_v5<<<temp_blocks, 256, 0, stream>>>(h2o, hist2, Whis, WT, fo);
    } else {
        sage_v5<25, false><<<sage_blocks, 256, 0, stream>>>(feats, feats, idx1, W1, h1o, nullptr);
        temporal_v5<<<temp_blocks, 256, 0, stream>>>(h1o, hist1, Whis, WT, fo);
        sage_v5<10, true><<<sage_blocks, 256, 0, stream>>>(fo, h1o, idx2, W2, h2o, fo);
        temporal_v5<<<temp_blocks, 256, 0, stream>>>(h2o, hist2, Whis, WT, fo);
    }
}

// Round 8
// 209.147 us; speedup vs baseline: 1.8120x; 1.1747x over previous
//
#include <hip/hip_runtime.h>
#include <hip/hip_bf16.h>

#define N_NODES 50000
#define NUM_P   20000
#define D_DIM   128
#define ALPHA_  0.2f
#define EPS_    1e-12f
#define NT      16      // nodes per block (50000 = 3125*16, 20000 = 1250*16)

typedef __attribute__((ext_vector_type(8))) short bf16x8;
typedef __attribute__((ext_vector_type(4))) float f32x4;

__device__ __forceinline__ float4 f4zero() { return make_float4(0.f, 0.f, 0.f, 0.f); }

__device__ __forceinline__ void scale4(float4& v, const float s) {
    v.x *= s; v.y *= s; v.z *= s; v.w *= s;
}

__device__ __forceinline__ short f2bf(float f) {
    __hip_bfloat16 h = __float2bfloat16(f);
    return *reinterpret_cast<short*>(&h);
}

__device__ __forceinline__ float bf2f(short u) {
    union { unsigned i; float f; } c;
    c.i = ((unsigned)(unsigned short)u) << 16;
    return c.f;
}

__device__ __forceinline__ short4 pack4(const float4 v) {
    short4 s;
    s.x = f2bf(v.x); s.y = f2bf(v.y); s.z = f2bf(v.z); s.w = f2bf(v.w);
    return s;
}

// ---------------------------------------------------------------------------
// Weight pre-transpose+cvt: o[sel][j][c] = bf16(W_sel[c][j]); o is [2][128][256].
// ---------------------------------------------------------------------------
__global__ __launch_bounds__(256)
void wcvt_kernel(const float* __restrict__ Wa, const float* __restrict__ Wb,
                 short* __restrict__ o)
{
    const int i = blockIdx.x * 256 + threadIdx.x;   // 0..65535
    const float* W = (i < 32768) ? Wa : Wb;
    const int t = i & 32767;
    const int j = t >> 8;        // 0..127
    const int c = t & 255;       // 0..255
    o[i] = f2bf(W[(size_t)c * D_DIM + j]);
}

// fp32 -> bf16 mirror (element-count must be multiple of 1024)
__global__ __launch_bounds__(256)
void fcvt_kernel(const float* __restrict__ in, short* __restrict__ o)
{
    const int i = blockIdx.x * 256 + threadIdx.x;
    const float4 v = reinterpret_cast<const float4*>(in)[i];
    reinterpret_cast<short4*>(o)[i] = pack4(v);
}

// ---------------------------------------------------------------------------
// MFMA SAGE v8: src is a bf16 [*,128] table. out0 fp32 (all rows);
// outb bf16 mirror (optional); out1 fp32 tail rows >= NUM_P (optional).
// ---------------------------------------------------------------------------
template<int K>
__global__ __launch_bounds__(256)
void sage_mfma8(const short* __restrict__ src,     // bf16 rows
                const int*   __restrict__ idx,
                const short* __restrict__ WTg,     // [128][256] bf16 = W^T
                float* __restrict__ out0,
                short* __restrict__ outb,
                float* __restrict__ out1)
{
    __shared__ __align__(16) char uni[NT * 132 * 4];   // xs (8192B) / ys (8448B)
    __shared__ float rnorm[NT];
    __shared__ int   sidx[NT * K];
    short* xs = reinterpret_cast<short*>(uni);          // [n][256] bf16, swizzled
    float* ys = reinterpret_cast<float*>(uni);          // [n][132] fp32

    const int tid  = threadIdx.x;
    const int base = blockIdx.x * NT;

    for (int i = tid; i < NT * K; i += 256)
        sidx[i] = idx[(size_t)base * K + i];
    __syncthreads();

    // ---- gather (bf16 rows, 256B each): 8 groups of 32 lanes ----
    {
        const int gp = tid >> 5;
        const int l  = tid & 31;
        for (int n = gp; n < NT; n += 8) {
            const int node = base + n;
            const short4 s4 = reinterpret_cast<const short4*>(src + (size_t)node * D_DIM)[l];
            float4 a4 = f4zero();
            for (int k = 0; k < K; ++k) {
                const int r = sidx[n * K + k];
                const short4 v4 = reinterpret_cast<const short4*>(src + (size_t)r * D_DIM)[l];
                a4.x += bf2f(v4.x); a4.y += bf2f(v4.y);
                a4.z += bf2f(v4.z); a4.w += bf2f(v4.w);
            }
            scale4(a4, 1.0f / (float)K);
            const int swzn = (n & 7) << 3;   // XOR swizzle in short units
            *reinterpret_cast<short4*>(&xs[n * 256 + ((l * 4) ^ swzn)])         = s4;
            *reinterpret_cast<short4*>(&xs[n * 256 + ((D_DIM + l * 4) ^ swzn)]) = pack4(a4);
        }
    }
    __syncthreads();

    // ---- MFMA: wave w -> cols [32w, 32w+32), K=256 in 8 steps ----
    const int w    = tid >> 6;
    const int l    = tid & 63;
    const int arow = l & 15;
    const int kg   = l >> 4;
    const int swz  = (arow & 7) << 3;

    f32x4 acc0 = {0.f, 0.f, 0.f, 0.f};
    f32x4 acc1 = {0.f, 0.f, 0.f, 0.f};
    const int colbase = w * 32;
    const short* b0 = WTg + (size_t)(colbase + arow) * 256 + kg * 8;
    const short* b1 = b0 + 16 * 256;

    #pragma unroll
    for (int step = 0; step < 8; ++step) {
        const int aoff = arow * 256 + ((step * 32 + kg * 8) ^ swz);
        const bf16x8 av  = *reinterpret_cast<const bf16x8*>(&xs[aoff]);
        const bf16x8 bv0 = *reinterpret_cast<const bf16x8*>(b0 + step * 32);
        const bf16x8 bv1 = *reinterpret_cast<const bf16x8*>(b1 + step * 32);
        acc0 = __builtin_amdgcn_mfma_f32_16x16x32_bf16(av, bv0, acc0, 0, 0, 0);
        acc1 = __builtin_amdgcn_mfma_f32_16x16x32_bf16(av, bv1, acc1, 0, 0, 0);
    }
    __syncthreads();   // all xs reads done before ys overlay writes

    // ---- epilogue: leaky -> ys (D layout: node=(l>>4)*4+r, col-local=l&15)
    {
        const int r0 = kg * 4;
        #pragma unroll
        for (int r = 0; r < 4; ++r) {
            float v0 = acc0[r]; v0 = v0 > 0.f ? v0 : ALPHA_ * v0;
            float v1 = acc1[r]; v1 = v1 > 0.f ? v1 : ALPHA_ * v1;
            ys[(r0 + r) * 132 + colbase + arow]      = v0;
            ys[(r0 + r) * 132 + colbase + 16 + arow] = v1;
        }
    }
    __syncthreads();

    // ---- row norms: 16 lanes per node ----
    {
        const int n  = tid >> 4;
        const int ll = tid & 15;
        float s = 0.f;
        #pragma unroll
        for (int jj = 0; jj < D_DIM; jj += 16) { const float t = ys[n * 132 + ll + jj]; s += t * t; }
        #pragma unroll
        for (int o = 8; o > 0; o >>= 1) s += __shfl_xor(s, o);
        if (ll == 0) rnorm[n] = 1.0f / fmaxf(sqrtf(s), EPS_);
    }
    __syncthreads();

    // ---- normalize + write ----
    {
        const int j = tid & 127;
        const int g = tid >> 7;
        #pragma unroll
        for (int r = 0; r < 8; ++r) {
            const int n    = g * 8 + r;
            const int node = base + n;
            const float v  = ys[n * 132 + j] * rnorm[n];
            out0[(size_t)node * D_DIM + j] = v;
            if (outb != nullptr) outb[(size_t)node * D_DIM + j] = f2bf(v);
            if (out1 != nullptr && node >= NUM_P) out1[(size_t)node * D_DIM + j] = v;
        }
    }
}

// ---------------------------------------------------------------------------
// Temporal (fp32, proven v5 structure). outp fp32 (nullable), outb bf16 (nullable).
// ---------------------------------------------------------------------------
__global__ __launch_bounds__(256)
void temporal_v8(const float* __restrict__ head,
                 const float* __restrict__ hist,
                 const float* __restrict__ Whis,
                 const float* __restrict__ WT,
                 float* __restrict__ outp,
                 short* __restrict__ outb)
{
    __shared__ float xs[NT][2 * D_DIM];
    __shared__ float hm[NT][D_DIM];
    __shared__ float rnorm[NT];

    const int tid  = threadIdx.x;
    const int base = blockIdx.x * NT;
    const size_t HS = (size_t)NUM_P * D_DIM;

    {
        const int gp = tid >> 5;
        const int l  = tid & 31;
        for (int n = gp; n < NT; n += 8) {
            const size_t off = (size_t)(base + n) * D_DIM;
            const float4 h4 = reinterpret_cast<const float4*>(head + off)[l];
            const float4 p0 = reinterpret_cast<const float4*>(hist + off)[l];
            const float4 p1 = reinterpret_cast<const float4*>(hist + off + HS)[l];
            const float4 p2 = reinterpret_cast<const float4*>(hist + off + 2 * HS)[l];
            float4 m4;
            m4.x = (p0.x + p1.x + p2.x) * (1.0f / 3.0f);
            m4.y = (p0.y + p1.y + p2.y) * (1.0f / 3.0f);
            m4.z = (p0.z + p1.z + p2.z) * (1.0f / 3.0f);
            m4.w = (p0.w + p1.w + p2.w) * (1.0f / 3.0f);
            reinterpret_cast<float4*>(&xs[n][0])[l] = h4;
            reinterpret_cast<float4*>(&hm[n][0])[l] = m4;
        }
    }
    __syncthreads();

    const int j  = tid & 127;
    const int g  = tid >> 7;
    const int nb = g * 8;

    {
        float a2[8];
        #pragma unroll
        for (int r = 0; r < 8; ++r) a2[r] = 0.f;
        for (int c4 = 0; c4 < D_DIM / 4; ++c4) {
            const int c = c4 * 4;
            const float w0 = Whis[(size_t)(c + 0) * D_DIM + j];
            const float w1 = Whis[(size_t)(c + 1) * D_DIM + j];
            const float w2 = Whis[(size_t)(c + 2) * D_DIM + j];
            const float w3 = Whis[(size_t)(c + 3) * D_DIM + j];
            #pragma unroll
            for (int r = 0; r < 8; ++r) {
                const float4 xv = *reinterpret_cast<const float4*>(&hm[nb + r][c]);
                a2[r] = fmaf(xv.w, w3, fmaf(xv.z, w2, fmaf(xv.y, w1, fmaf(xv.x, w0, a2[r]))));
            }
        }
        __syncthreads();
        #pragma unroll
        for (int r = 0; r < 8; ++r) xs[nb + r][D_DIM + j] = a2[r];
    }
    __syncthreads();

    float acc[8];
    #pragma unroll
    for (int r = 0; r < 8; ++r) acc[r] = 0.f;
    for (int c4 = 0; c4 < (2 * D_DIM) / 4; ++c4) {
        const int c = c4 * 4;
        const float w0 = WT[(size_t)(c + 0) * D_DIM + j];
        const float w1 = WT[(size_t)(c + 1) * D_DIM + j];
        const float w2 = WT[(size_t)(c + 2) * D_DIM + j];
        const float w3 = WT[(size_t)(c + 3) * D_DIM + j];
        #pragma unroll
        for (int r = 0; r < 8; ++r) {
            const float4 xv = *reinterpret_cast<const float4*>(&xs[nb + r][c]);
            acc[r] = fmaf(xv.w, w3, fmaf(xv.z, w2, fmaf(xv.y, w1, fmaf(xv.x, w0, acc[r]))));
        }
    }
    __syncthreads();

    #pragma unroll
    for (int r = 0; r < 8; ++r) {
        float v = acc[r];
        v = v > 0.f ? v : ALPHA_ * v;
        xs[nb + r][j] = v;
    }
    __syncthreads();

    {
        const int n  = tid >> 4;
        const int ll = tid & 15;
        float s = 0.f;
        #pragma unroll
        for (int jj = ll; jj < D_DIM; jj += 16) { const float t = xs[n][jj]; s += t * t; }
        #pragma unroll
        for (int o = 8; o > 0; o >>= 1) s += __shfl_xor(s, o);
        if (ll == 0) rnorm[n] = 1.0f / fmaxf(sqrtf(s), EPS_);
    }
    __syncthreads();

    #pragma unroll
    for (int r = 0; r < 8; ++r) {
        const int n = nb + r;
        const float v = xs[n][j] * rnorm[n];
        const size_t o = (size_t)(base + n) * D_DIM + j;
        if (outp != nullptr) outp[o] = v;
        if (outb != nullptr) outb[o] = f2bf(v);
    }
}

// ---------------------------------------------------------------------------
// Fallback fp32 SAGE (v5, proven): used when ws_size is too small.
// ---------------------------------------------------------------------------
template<int K, bool SPLIT>
__global__ __launch_bounds__(256)
void sage_v5(const float* __restrict__ srcLow,
             const float* __restrict__ srcHigh,
             const int*   __restrict__ idx,
             const float* __restrict__ W,
             float* __restrict__ out0,
             float* __restrict__ out1)
{
    __shared__ float xs[NT][2 * D_DIM];
    __shared__ int   sidx[NT * K];
    __shared__ float rnorm[NT];

    const int tid  = threadIdx.x;
    const int base = blockIdx.x * NT;

    for (int i = tid; i < NT * K; i += 256)
        sidx[i] = idx[(size_t)base * K + i];
    __syncthreads();

    {
        const int gp = tid >> 5;
        const int l  = tid & 31;
        for (int n = gp; n < NT; n += 8) {
            const int node = base + n;
            const float* sp = (!SPLIT || node < NUM_P) ? srcLow : srcHigh;
            const float4 s4 = reinterpret_cast<const float4*>(sp + (size_t)node * D_DIM)[l];
            float4 a4 = f4zero();
            for (int k = 0; k < K; ++k) {
                const int r = sidx[n * K + k];
                const float* rp = (!SPLIT || r < NUM_P) ? srcLow : srcHigh;
                const float4 v4 = reinterpret_cast<const float4*>(rp + (size_t)r * D_DIM)[l];
                a4.x += v4.x; a4.y += v4.y; a4.z += v4.z; a4.w += v4.w;
            }
            scale4(a4, 1.0f / (float)K);
            reinterpret_cast<float4*>(&xs[n][0])[l]     = s4;
            reinterpret_cast<float4*>(&xs[n][D_DIM])[l] = a4;
        }
    }
    __syncthreads();

    const int j  = tid & 127;
    const int g  = tid >> 7;
    const int nb = g * 8;

    float acc[8];
    #pragma unroll
    for (int r = 0; r < 8; ++r) acc[r] = 0.f;
    for (int c4 = 0; c4 < (2 * D_DIM) / 4; ++c4) {
        const int c = c4 * 4;
        const float w0 = W[(size_t)(c + 0) * D_DIM + j];
        const float w1 = W[(size_t)(c + 1) * D_DIM + j];
        const float w2 = W[(size_t)(c + 2) * D_DIM + j];
        const float w3 = W[(size_t)(c + 3) * D_DIM + j];
        #pragma unroll
        for (int r = 0; r < 8; ++r) {
            const float4 xv = *reinterpret_cast<const float4*>(&xs[nb + r][c]);
            acc[r] = fmaf(xv.w, w3, fmaf(xv.z, w2, fmaf(xv.y, w1, fmaf(xv.x, w0, acc[r]))));
        }
    }
    __syncthreads();

    #pragma unroll
    for (int r = 0; r < 8; ++r) {
        float v = acc[r];
        v = v > 0.f ? v : ALPHA_ * v;
        xs[nb + r][j] = v;
    }
    __syncthreads();

    {
        const int n  = tid >> 4;
        const int ll = tid & 15;
        float s = 0.f;
        #pragma unroll
        for (int jj = ll; jj < D_DIM; jj += 16) { const float t = xs[n][jj]; s += t * t; }
        #pragma unroll
        for (int o = 8; o > 0; o >>= 1) s += __shfl_xor(s, o);
        if (ll == 0) rnorm[n] = 1.0f / fmaxf(sqrtf(s), EPS_);
    }
    __syncthreads();

    #pragma unroll
    for (int r = 0; r < 8; ++r) {
        const int n    = nb + r;
        const int node = base + n;
        const float v  = xs[n][j] * rnorm[n];
        out0[(size_t)node * D_DIM + j] = v;
        if (out1 != nullptr && node >= NUM_P) out1[(size_t)node * D_DIM + j] = v;
    }
}

// ---------------------------------------------------------------------------
extern "C" void kernel_launch(void* const* d_in, const int* in_sizes, int n_in,
                              void* d_out, int out_size, void* d_ws, size_t ws_size,
                              hipStream_t stream)
{
    (void)in_sizes; (void)n_in; (void)out_size;

    const float* feats = (const float*)d_in[0];
    const int*   idx1  = (const int*)  d_in[1];
    const int*   idx2  = (const int*)  d_in[2];
    const float* hist1 = (const float*)d_in[3];
    const float* hist2 = (const float*)d_in[4];
    const float* W1    = (const float*)d_in[5];
    const float* W2    = (const float*)d_in[6];
    const float* Whis  = (const float*)d_in[7];
    const float* WT    = (const float*)d_in[8];

    float* out = (float*)d_out;
    float* h1o = out;
    float* h2o = out + (size_t)N_NODES * D_DIM;
    float* fo  = out + 2 * (size_t)N_NODES * D_DIM;

    const int sage_blocks = N_NODES / NT;  // 3125
    const int temp_blocks = NUM_P   / NT;  // 1250

    const size_t SZ_N = (size_t)N_NODES * D_DIM;           // 6.4M elems
    const size_t need = (2u * 32768u + 2u * SZ_N) * 2u;    // WT x2 + fb + hb, bf16

    if (ws_size >= need) {
        short* W1Tg = (short*)d_ws;          // [128][256] bf16
        short* W2Tg = W1Tg + 32768;
        short* fb   = W2Tg + 32768;          // bf16 feats   [N,128]
        short* hb   = fb + SZ_N;             // bf16 h1/f1   [N,128]

        wcvt_kernel<<<256, 256, 0, stream>>>(W1, W2, W1Tg);
        fcvt_kernel<<<(int)(SZ_N / 1024), 256, 0, stream>>>(feats, fb);

        // h1 = sage(feats, idx1, W1): fp32 -> h1o, bf16 -> hb
        sage_mfma8<25><<<sage_blocks, 256, 0, stream>>>(fb, idx1, W1Tg, h1o, hb, nullptr);
        // f1 -> bf16 into hb rows [0, NUM) only (fo rows <NUM are dead until f2)
        temporal_v8<<<temp_blocks, 256, 0, stream>>>(h1o, hist1, Whis, WT, nullptr, hb);
        // h2 = sage(hb, idx2, W2): fp32 -> h2o, tail fp32 -> fo
        sage_mfma8<10><<<sage_blocks, 256, 0, stream>>>(hb, idx2, W2Tg, h2o, nullptr, fo);
        // f2 -> fo rows [0, NUM)
        temporal_v8<<<temp_blocks, 256, 0, stream>>>(h2o, hist2, Whis, WT, fo, nullptr);
    } else {
        sage_v5<25, false><<<sage_blocks, 256, 0, stream>>>(feats, feats, idx1, W1, h1o, nullptr);
        temporal_v8<<<temp_blocks, 256, 0, stream>>>(h1o, hist1, Whis, WT, fo, nullptr);
        sage_v5<10, true><<<sage_blocks, 256, 0, stream>>>(fo, h1o, idx2, W2, h2o, fo);
        temporal_v8<<<temp_blocks, 256, 0, stream>>>(h2o, hist2, Whis, WT, fo, nullptr);
    }
}

// Round 9
// 156.389 us; speedup vs baseline: 2.4233x; 1.3374x over previous
//
#include <hip/hip_runtime.h>
#include <hip/hip_bf16.h>

#define N_NODES 50000
#define NUM_P   20000
#define D_DIM   128
#define ALPHA_  0.2f
#define EPS_    1e-12f
#define NT      16      // nodes per block (50000 = 3125*16, 20000 = 1250*16)

typedef __attribute__((ext_vector_type(8))) short bf16x8;
typedef __attribute__((ext_vector_type(4))) float f32x4;

__device__ __forceinline__ float4 f4zero() { return make_float4(0.f, 0.f, 0.f, 0.f); }

__device__ __forceinline__ void scale4(float4& v, const float s) {
    v.x *= s; v.y *= s; v.z *= s; v.w *= s;
}

__device__ __forceinline__ short f2bf(float f) {
    __hip_bfloat16 h = __float2bfloat16(f);
    return *reinterpret_cast<short*>(&h);
}

__device__ __forceinline__ float bf2f(short u) {
    union { unsigned i; float f; } c;
    c.i = ((unsigned)(unsigned short)u) << 16;
    return c.f;
}

__device__ __forceinline__ short4 pack4(const float4 v) {
    short4 s;
    s.x = f2bf(v.x); s.y = f2bf(v.y); s.z = f2bf(v.z); s.w = f2bf(v.w);
    return s;
}

// ---------------------------------------------------------------------------
// Weight pre-transpose+cvt to bf16:
//   o[0..32768)        = W1^T  [128 col][256 k]
//   o[32768..65536)    = W2^T  [128 col][256 k]
//   o[65536..81920)    = Whis^T[128 col][128 k]
//   o[81920..114688)   = WT^T  [128 col][256 k]
// ---------------------------------------------------------------------------
__global__ __launch_bounds__(256)
void wcvt2_kernel(const float* __restrict__ W1, const float* __restrict__ W2,
                  const float* __restrict__ Whis, const float* __restrict__ WTm,
                  short* __restrict__ o)
{
    const int i = blockIdx.x * 256 + threadIdx.x;   // 0..114687
    float v;
    if (i < 65536) {
        const float* W = (i < 32768) ? W1 : W2;
        const int t = i & 32767;
        v = W[(size_t)(t & 255) * D_DIM + (t >> 8)];
    } else if (i < 81920) {
        const int t = i - 65536;
        v = Whis[(size_t)(t & 127) * D_DIM + (t >> 7)];
    } else {
        const int t = i - 81920;
        v = WTm[(size_t)(t & 255) * D_DIM + (t >> 8)];
    }
    o[i] = f2bf(v);
}

// fp32 -> bf16 mirror (element count multiple of 1024)
__global__ __launch_bounds__(256)
void fcvt_kernel(const float* __restrict__ in, short* __restrict__ o)
{
    const int i = blockIdx.x * 256 + threadIdx.x;
    const float4 v = reinterpret_cast<const float4*>(in)[i];
    reinterpret_cast<short4*>(o)[i] = pack4(v);
}

// ---------------------------------------------------------------------------
// MFMA SAGE: src bf16 [*,128]. out0 fp32 all rows; outb bf16 rows < nb_limit;
// out1 fp32 rows >= NUM_P (feat tail).
// ---------------------------------------------------------------------------
template<int K>
__global__ __launch_bounds__(256)
void sage_mfma8(const short* __restrict__ src,
                const int*   __restrict__ idx,
                const short* __restrict__ WTg,     // [128][256] bf16 = W^T
                float* __restrict__ out0,
                short* __restrict__ outb,
                int nb_limit,
                float* __restrict__ out1)
{
    __shared__ __align__(16) char uni[NT * 132 * 4];
    __shared__ float rnorm[NT];
    __shared__ int   sidx[NT * K];
    short* xs = reinterpret_cast<short*>(uni);   // [n][256] bf16, swizzled
    float* ys = reinterpret_cast<float*>(uni);   // [n][132] fp32

    const int tid  = threadIdx.x;
    const int base = blockIdx.x * NT;

    for (int i = tid; i < NT * K; i += 256)
        sidx[i] = idx[(size_t)base * K + i];
    __syncthreads();

    // ---- gather (bf16 rows, 256B): 8 groups of 32 lanes ----
    {
        const int gp = tid >> 5;
        const int l  = tid & 31;
        for (int n = gp; n < NT; n += 8) {
            const int node = base + n;
            const short4 s4 = reinterpret_cast<const short4*>(src + (size_t)node * D_DIM)[l];
            float4 a4 = f4zero();
            for (int k = 0; k < K; ++k) {
                const int r = sidx[n * K + k];
                const short4 v4 = reinterpret_cast<const short4*>(src + (size_t)r * D_DIM)[l];
                a4.x += bf2f(v4.x); a4.y += bf2f(v4.y);
                a4.z += bf2f(v4.z); a4.w += bf2f(v4.w);
            }
            scale4(a4, 1.0f / (float)K);
            const int swzn = (n & 7) << 3;
            *reinterpret_cast<short4*>(&xs[n * 256 + ((l * 4) ^ swzn)])         = s4;
            *reinterpret_cast<short4*>(&xs[n * 256 + ((D_DIM + l * 4) ^ swzn)]) = pack4(a4);
        }
    }
    __syncthreads();

    // ---- MFMA: wave w -> cols [32w, 32w+32), K=256 in 8 steps ----
    const int w    = tid >> 6;
    const int l    = tid & 63;
    const int arow = l & 15;
    const int kg   = l >> 4;
    const int swz  = (arow & 7) << 3;

    f32x4 acc0 = {0.f, 0.f, 0.f, 0.f};
    f32x4 acc1 = {0.f, 0.f, 0.f, 0.f};
    const int colbase = w * 32;
    const short* b0 = WTg + (size_t)(colbase + arow) * 256 + kg * 8;
    const short* b1 = b0 + 16 * 256;

    #pragma unroll
    for (int step = 0; step < 8; ++step) {
        const int aoff = arow * 256 + ((step * 32 + kg * 8) ^ swz);
        const bf16x8 av  = *reinterpret_cast<const bf16x8*>(&xs[aoff]);
        const bf16x8 bv0 = *reinterpret_cast<const bf16x8*>(b0 + step * 32);
        const bf16x8 bv1 = *reinterpret_cast<const bf16x8*>(b1 + step * 32);
        acc0 = __builtin_amdgcn_mfma_f32_16x16x32_bf16(av, bv0, acc0, 0, 0, 0);
        acc1 = __builtin_amdgcn_mfma_f32_16x16x32_bf16(av, bv1, acc1, 0, 0, 0);
    }
    __syncthreads();

    // ---- epilogue: leaky -> ys (D layout: node=(l>>4)*4+r, col-local=l&15)
    {
        const int r0 = kg * 4;
        #pragma unroll
        for (int r = 0; r < 4; ++r) {
            float v0 = acc0[r]; v0 = v0 > 0.f ? v0 : ALPHA_ * v0;
            float v1 = acc1[r]; v1 = v1 > 0.f ? v1 : ALPHA_ * v1;
            ys[(r0 + r) * 132 + colbase + arow]      = v0;
            ys[(r0 + r) * 132 + colbase + 16 + arow] = v1;
        }
    }
    __syncthreads();

    {
        const int n  = tid >> 4;
        const int ll = tid & 15;
        float s = 0.f;
        #pragma unroll
        for (int jj = 0; jj < D_DIM; jj += 16) { const float t = ys[n * 132 + ll + jj]; s += t * t; }
        #pragma unroll
        for (int o = 8; o > 0; o >>= 1) s += __shfl_xor(s, o);
        if (ll == 0) rnorm[n] = 1.0f / fmaxf(sqrtf(s), EPS_);
    }
    __syncthreads();

    {
        const int j = tid & 127;
        const int g = tid >> 7;
        #pragma unroll
        for (int r = 0; r < 8; ++r) {
            const int n    = g * 8 + r;
            const int node = base + n;
            const float v  = ys[n * 132 + j] * rnorm[n];
            out0[(size_t)node * D_DIM + j] = v;
            if (outb != nullptr && node < nb_limit) outb[(size_t)node * D_DIM + j] = f2bf(v);
            if (out1 != nullptr && node >= NUM_P)   out1[(size_t)node * D_DIM + j] = v;
        }
    }
}

// ---------------------------------------------------------------------------
// MFMA temporal: out = l2norm(leaky([head | (mean_p hist)@Whis] @ WT)).
// head: bf16 table (rows < NUM_P). headb/outb may ALIAS (per-row read-then-
// write within the owning block only) -> no __restrict__ on them.
// ---------------------------------------------------------------------------
__global__ __launch_bounds__(256)
void temporal_mfma(const short* headb,                 // bf16 [NUM_P+,128]
                   const float* __restrict__ hist,     // [3][NUM_P][128] fp32
                   const short* __restrict__ WhisTg,   // [128][128] bf16 = Whis^T
                   const short* __restrict__ WTTg,     // [128][256] bf16 = WT^T
                   float* __restrict__ outp,           // fp32, nullable
                   short* outb)                        // bf16, nullable (may alias headb)
{
    __shared__ __align__(16) char uni[NT * 132 * 4];
    __shared__ float rnorm[NT];
    short* xs = reinterpret_cast<short*>(uni);   // [n][256] bf16 swizzled: head | hm->tf
    float* ys = reinterpret_cast<float*>(uni);   // [n][132] fp32

    const int tid  = threadIdx.x;
    const int base = blockIdx.x * NT;
    const size_t HS = (size_t)NUM_P * D_DIM;

    // ---- phase 1: head (bf16 copy) + hist mean (fp32 -> bf16), swizzled ----
    {
        const int gp = tid >> 5;
        const int l  = tid & 31;
        for (int n = gp; n < NT; n += 8) {
            const size_t off = (size_t)(base + n) * D_DIM;
            const short4 h4 = reinterpret_cast<const short4*>(headb + off)[l];
            const float4 p0 = reinterpret_cast<const float4*>(hist + off)[l];
            const float4 p1 = reinterpret_cast<const float4*>(hist + off + HS)[l];
            const float4 p2 = reinterpret_cast<const float4*>(hist + off + 2 * HS)[l];
            float4 m4;
            m4.x = (p0.x + p1.x + p2.x) * (1.0f / 3.0f);
            m4.y = (p0.y + p1.y + p2.y) * (1.0f / 3.0f);
            m4.z = (p0.z + p1.z + p2.z) * (1.0f / 3.0f);
            m4.w = (p0.w + p1.w + p2.w) * (1.0f / 3.0f);
            const int swzn = (n & 7) << 3;
            *reinterpret_cast<short4*>(&xs[n * 256 + ((l * 4) ^ swzn)])         = h4;
            *reinterpret_cast<short4*>(&xs[n * 256 + ((D_DIM + l * 4) ^ swzn)]) = pack4(m4);
        }
    }
    __syncthreads();

    const int w    = tid >> 6;
    const int l    = tid & 63;
    const int arow = l & 15;
    const int kg   = l >> 4;
    const int swz  = (arow & 7) << 3;
    const int colbase = w * 32;

    // ---- MFMA-A: tf = hm @ Whis^T (K=128, 4 steps), no activation ----
    {
        f32x4 t0 = {0.f, 0.f, 0.f, 0.f};
        f32x4 t1 = {0.f, 0.f, 0.f, 0.f};
        const short* b0 = WhisTg + (size_t)(colbase + arow) * 128 + kg * 8;
        const short* b1 = b0 + 16 * 128;
        #pragma unroll
        for (int step = 0; step < 4; ++step) {
            const int aoff = arow * 256 + ((D_DIM + step * 32 + kg * 8) ^ swz);
            const bf16x8 av  = *reinterpret_cast<const bf16x8*>(&xs[aoff]);
            const bf16x8 bv0 = *reinterpret_cast<const bf16x8*>(b0 + step * 32);
            const bf16x8 bv1 = *reinterpret_cast<const bf16x8*>(b1 + step * 32);
            t0 = __builtin_amdgcn_mfma_f32_16x16x32_bf16(av, bv0, t0, 0, 0, 0);
            t1 = __builtin_amdgcn_mfma_f32_16x16x32_bf16(av, bv1, t1, 0, 0, 0);
        }
        __syncthreads();   // all hm reads done before overwrite

        // write tf back in place of hm (bf16, swizzled A layout)
        #pragma unroll
        for (int r = 0; r < 4; ++r) {
            const int node = kg * 4 + r;
            const int swzn = (node & 7) << 3;
            xs[node * 256 + ((D_DIM + colbase + arow) ^ swzn)]      = f2bf(t0[r]);
            xs[node * 256 + ((D_DIM + colbase + 16 + arow) ^ swzn)] = f2bf(t1[r]);
        }
    }
    __syncthreads();

    // ---- MFMA-B: y = [head | tf] @ WT^T (K=256, 8 steps) ----
    f32x4 acc0 = {0.f, 0.f, 0.f, 0.f};
    f32x4 acc1 = {0.f, 0.f, 0.f, 0.f};
    {
        const short* b0 = WTTg + (size_t)(colbase + arow) * 256 + kg * 8;
        const short* b1 = b0 + 16 * 256;
        #pragma unroll
        for (int step = 0; step < 8; ++step) {
            const int aoff = arow * 256 + ((step * 32 + kg * 8) ^ swz);
            const bf16x8 av  = *reinterpret_cast<const bf16x8*>(&xs[aoff]);
            const bf16x8 bv0 = *reinterpret_cast<const bf16x8*>(b0 + step * 32);
            const bf16x8 bv1 = *reinterpret_cast<const bf16x8*>(b1 + step * 32);
            acc0 = __builtin_amdgcn_mfma_f32_16x16x32_bf16(av, bv0, acc0, 0, 0, 0);
            acc1 = __builtin_amdgcn_mfma_f32_16x16x32_bf16(av, bv1, acc1, 0, 0, 0);
        }
    }
    __syncthreads();

    // ---- epilogue: leaky -> ys ----
    {
        const int r0 = kg * 4;
        #pragma unroll
        for (int r = 0; r < 4; ++r) {
            float v0 = acc0[r]; v0 = v0 > 0.f ? v0 : ALPHA_ * v0;
            float v1 = acc1[r]; v1 = v1 > 0.f ? v1 : ALPHA_ * v1;
            ys[(r0 + r) * 132 + colbase + arow]      = v0;
            ys[(r0 + r) * 132 + colbase + 16 + arow] = v1;
        }
    }
    __syncthreads();

    {
        const int n  = tid >> 4;
        const int ll = tid & 15;
        float s = 0.f;
        #pragma unroll
        for (int jj = 0; jj < D_DIM; jj += 16) { const float t = ys[n * 132 + ll + jj]; s += t * t; }
        #pragma unroll
        for (int o = 8; o > 0; o >>= 1) s += __shfl_xor(s, o);
        if (ll == 0) rnorm[n] = 1.0f / fmaxf(sqrtf(s), EPS_);
    }
    __syncthreads();

    {
        const int j = tid & 127;
        const int g = tid >> 7;
        #pragma unroll
        for (int r = 0; r < 8; ++r) {
            const int n = g * 8 + r;
            const float v = ys[n * 132 + j] * rnorm[n];
            const size_t o = (size_t)(base + n) * D_DIM + j;
            if (outp != nullptr) outp[o] = v;
            if (outb != nullptr) outb[o] = f2bf(v);
        }
    }
}

// ---------------------------------------------------------------------------
// fp32 temporal (proven, fallback paths)
// ---------------------------------------------------------------------------
__global__ __launch_bounds__(256)
void temporal_v8(const float* __restrict__ head,
                 const float* __restrict__ hist,
                 const float* __restrict__ Whis,
                 const float* __restrict__ WTm,
                 float* __restrict__ outp,
                 short* __restrict__ outb)
{
    __shared__ float xs[NT][2 * D_DIM];
    __shared__ float hm[NT][D_DIM];
    __shared__ float rnorm[NT];

    const int tid  = threadIdx.x;
    const int base = blockIdx.x * NT;
    const size_t HS = (size_t)NUM_P * D_DIM;

    {
        const int gp = tid >> 5;
        const int l  = tid & 31;
        for (int n = gp; n < NT; n += 8) {
            const size_t off = (size_t)(base + n) * D_DIM;
            const float4 h4 = reinterpret_cast<const float4*>(head + off)[l];
            const float4 p0 = reinterpret_cast<const float4*>(hist + off)[l];
            const float4 p1 = reinterpret_cast<const float4*>(hist + off + HS)[l];
            const float4 p2 = reinterpret_cast<const float4*>(hist + off + 2 * HS)[l];
            float4 m4;
            m4.x = (p0.x + p1.x + p2.x) * (1.0f / 3.0f);
            m4.y = (p0.y + p1.y + p2.y) * (1.0f / 3.0f);
            m4.z = (p0.z + p1.z + p2.z) * (1.0f / 3.0f);
            m4.w = (p0.w + p1.w + p2.w) * (1.0f / 3.0f);
            reinterpret_cast<float4*>(&xs[n][0])[l] = h4;
            reinterpret_cast<float4*>(&hm[n][0])[l] = m4;
        }
    }
    __syncthreads();

    const int j  = tid & 127;
    const int g  = tid >> 7;
    const int nb = g * 8;

    {
        float a2[8];
        #pragma unroll
        for (int r = 0; r < 8; ++r) a2[r] = 0.f;
        for (int c4 = 0; c4 < D_DIM / 4; ++c4) {
            const int c = c4 * 4;
            const float w0 = Whis[(size_t)(c + 0) * D_DIM + j];
            const float w1 = Whis[(size_t)(c + 1) * D_DIM + j];
            const float w2 = Whis[(size_t)(c + 2) * D_DIM + j];
            const float w3 = Whis[(size_t)(c + 3) * D_DIM + j];
            #pragma unroll
            for (int r = 0; r < 8; ++r) {
                const float4 xv = *reinterpret_cast<const float4*>(&hm[nb + r][c]);
                a2[r] = fmaf(xv.w, w3, fmaf(xv.z, w2, fmaf(xv.y, w1, fmaf(xv.x, w0, a2[r]))));
            }
        }
        __syncthreads();
        #pragma unroll
        for (int r = 0; r < 8; ++r) xs[nb + r][D_DIM + j] = a2[r];
    }
    __syncthreads();

    float acc[8];
    #pragma unroll
    for (int r = 0; r < 8; ++r) acc[r] = 0.f;
    for (int c4 = 0; c4 < (2 * D_DIM) / 4; ++c4) {
        const int c = c4 * 4;
        const float w0 = WTm[(size_t)(c + 0) * D_DIM + j];
        const float w1 = WTm[(size_t)(c + 1) * D_DIM + j];
        const float w2 = WTm[(size_t)(c + 2) * D_DIM + j];
        const float w3 = WTm[(size_t)(c + 3) * D_DIM + j];
        #pragma unroll
        for (int r = 0; r < 8; ++r) {
            const float4 xv = *reinterpret_cast<const float4*>(&xs[nb + r][c]);
            acc[r] = fmaf(xv.w, w3, fmaf(xv.z, w2, fmaf(xv.y, w1, fmaf(xv.x, w0, acc[r]))));
        }
    }
    __syncthreads();

    #pragma unroll
    for (int r = 0; r < 8; ++r) {
        float v = acc[r];
        v = v > 0.f ? v : ALPHA_ * v;
        xs[nb + r][j] = v;
    }
    __syncthreads();

    {
        const int n  = tid >> 4;
        const int ll = tid & 15;
        float s = 0.f;
        #pragma unroll
        for (int jj = ll; jj < D_DIM; jj += 16) { const float t = xs[n][jj]; s += t * t; }
        #pragma unroll
        for (int o = 8; o > 0; o >>= 1) s += __shfl_xor(s, o);
        if (ll == 0) rnorm[n] = 1.0f / fmaxf(sqrtf(s), EPS_);
    }
    __syncthreads();

    #pragma unroll
    for (int r = 0; r < 8; ++r) {
        const int n = nb + r;
        const float v = xs[n][j] * rnorm[n];
        const size_t o = (size_t)(base + n) * D_DIM + j;
        if (outp != nullptr) outp[o] = v;
        if (outb != nullptr) outb[o] = f2bf(v);
    }
}

// ---------------------------------------------------------------------------
// fp32 SAGE (last-resort fallback, no workspace)
// ---------------------------------------------------------------------------
template<int K, bool SPLIT>
__global__ __launch_bounds__(256)
void sage_v5(const float* __restrict__ srcLow,
             const float* __restrict__ srcHigh,
             const int*   __restrict__ idx,
             const float* __restrict__ W,
             float* __restrict__ out0,
             float* __restrict__ out1)
{
    __shared__ float xs[NT][2 * D_DIM];
    __shared__ int   sidx[NT * K];
    __shared__ float rnorm[NT];

    const int tid  = threadIdx.x;
    const int base = blockIdx.x * NT;

    for (int i = tid; i < NT * K; i += 256)
        sidx[i] = idx[(size_t)base * K + i];
    __syncthreads();

    {
        const int gp = tid >> 5;
        const int l  = tid & 31;
        for (int n = gp; n < NT; n += 8) {
            const int node = base + n;
            const float* sp = (!SPLIT || node < NUM_P) ? srcLow : srcHigh;
            const float4 s4 = reinterpret_cast<const float4*>(sp + (size_t)node * D_DIM)[l];
            float4 a4 = f4zero();
            for (int k = 0; k < K; ++k) {
                const int r = sidx[n * K + k];
                const float* rp = (!SPLIT || r < NUM_P) ? srcLow : srcHigh;
                const float4 v4 = reinterpret_cast<const float4*>(rp + (size_t)r * D_DIM)[l];
                a4.x += v4.x; a4.y += v4.y; a4.z += v4.z; a4.w += v4.w;
            }
            scale4(a4, 1.0f / (float)K);
            reinterpret_cast<float4*>(&xs[n][0])[l]     = s4;
            reinterpret_cast<float4*>(&xs[n][D_DIM])[l] = a4;
        }
    }
    __syncthreads();

    const int j  = tid & 127;
    const int g  = tid >> 7;
    const int nb = g * 8;

    float acc[8];
    #pragma unroll
    for (int r = 0; r < 8; ++r) acc[r] = 0.f;
    for (int c4 = 0; c4 < (2 * D_DIM) / 4; ++c4) {
        const int c = c4 * 4;
        const float w0 = W[(size_t)(c + 0) * D_DIM + j];
        const float w1 = W[(size_t)(c + 1) * D_DIM + j];
        const float w2 = W[(size_t)(c + 2) * D_DIM + j];
        const float w3 = W[(size_t)(c + 3) * D_DIM + j];
        #pragma unroll
        for (int r = 0; r < 8; ++r) {
            const float4 xv = *reinterpret_cast<const float4*>(&xs[nb + r][c]);
            acc[r] = fmaf(xv.w, w3, fmaf(xv.z, w2, fmaf(xv.y, w1, fmaf(xv.x, w0, acc[r]))));
        }
    }
    __syncthreads();

    #pragma unroll
    for (int r = 0; r < 8; ++r) {
        float v = acc[r];
        v = v > 0.f ? v : ALPHA_ * v;
        xs[nb + r][j] = v;
    }
    __syncthreads();

    {
        const int n  = tid >> 4;
        const int ll = tid & 15;
        float s = 0.f;
        #pragma unroll
        for (int jj = ll; jj < D_DIM; jj += 16) { const float t = xs[n][jj]; s += t * t; }
        #pragma unroll
        for (int o = 8; o > 0; o >>= 1) s += __shfl_xor(s, o);
        if (ll == 0) rnorm[n] = 1.0f / fmaxf(sqrtf(s), EPS_);
    }
    __syncthreads();

    #pragma unroll
    for (int r = 0; r < 8; ++r) {
        const int n    = nb + r;
        const int node = base + n;
        const float v  = xs[n][j] * rnorm[n];
        out0[(size_t)node * D_DIM + j] = v;
        if (out1 != nullptr && node >= NUM_P) out1[(size_t)node * D_DIM + j] = v;
    }
}

// ---------------------------------------------------------------------------
extern "C" void kernel_launch(void* const* d_in, const int* in_sizes, int n_in,
                              void* d_out, int out_size, void* d_ws, size_t ws_size,
                              hipStream_t stream)
{
    (void)in_sizes; (void)n_in; (void)out_size;

    const float* feats = (const float*)d_in[0];
    const int*   idx1  = (const int*)  d_in[1];
    const int*   idx2  = (const int*)  d_in[2];
    const float* hist1 = (const float*)d_in[3];
    const float* hist2 = (const float*)d_in[4];
    const float* W1    = (const float*)d_in[5];
    const float* W2    = (const float*)d_in[6];
    const float* Whis  = (const float*)d_in[7];
    const float* WTm   = (const float*)d_in[8];

    float* out = (float*)d_out;
    float* h1o = out;
    float* h2o = out + (size_t)N_NODES * D_DIM;
    float* fo  = out + 2 * (size_t)N_NODES * D_DIM;

    const int sage_blocks = N_NODES / NT;  // 3125
    const int temp_blocks = NUM_P   / NT;  // 1250

    const size_t SZ_N  = (size_t)N_NODES * D_DIM;   // 6.4M elems
    const size_t SZ_P  = (size_t)NUM_P  * D_DIM;    // 2.56M elems
    const size_t WOFF  = 114688;                     // all 4 transposed weights (shorts)
    const size_t needA = (WOFF + 2 * SZ_N + SZ_P) * 2;   // ~30.9 MB
    const size_t needB = (WOFF + 2 * SZ_N) * 2;          // ~25.8 MB

    short* wsp  = (short*)d_ws;
    short* W1T  = wsp;
    short* W2T  = wsp + 32768;
    short* WhT  = wsp + 65536;
    short* WTT  = wsp + 81920;
    short* fb   = wsp + WOFF;          // bf16 feats  [N,128]
    short* hb   = fb + SZ_N;           // bf16 h1/f1  [N,128]
    short* h2b  = hb + SZ_N;           // bf16 h2     [NUM_P,128]

    if (ws_size >= needA) {
        wcvt2_kernel<<<448, 256, 0, stream>>>(W1, W2, Whis, WTm, wsp);
        fcvt_kernel<<<(int)(SZ_N / 1024), 256, 0, stream>>>(feats, fb);

        // h1: fp32 -> h1o, bf16 -> hb (all rows; sage2 gathers any row)
        sage_mfma8<25><<<sage_blocks, 256, 0, stream>>>(fb, idx1, W1T, h1o, hb, N_NODES, nullptr);
        // f1: bf16 -> hb rows [0,NUM) (reads hb as head; per-row read-then-write in-block)
        temporal_mfma<<<temp_blocks, 256, 0, stream>>>(hb, hist1, WhT, WTT, nullptr, hb);
        // h2: fp32 -> h2o, bf16 rows<NUM -> h2b, fp32 tail -> fo
        sage_mfma8<10><<<sage_blocks, 256, 0, stream>>>(hb, idx2, W2T, h2o, h2b, NUM_P, fo);
        // f2: fp32 -> fo rows [0,NUM)
        temporal_mfma<<<temp_blocks, 256, 0, stream>>>(h2b, hist2, WhT, WTT, fo, nullptr);
    } else if (ws_size >= needB) {
        wcvt2_kernel<<<448, 256, 0, stream>>>(W1, W2, Whis, WTm, wsp);
        fcvt_kernel<<<(int)(SZ_N / 1024), 256, 0, stream>>>(feats, fb);

        sage_mfma8<25><<<sage_blocks, 256, 0, stream>>>(fb, idx1, W1T, h1o, hb, N_NODES, nullptr);
        temporal_v8<<<temp_blocks, 256, 0, stream>>>(h1o, hist1, Whis, WTm, nullptr, hb);
        sage_mfma8<10><<<sage_blocks, 256, 0, stream>>>(hb, idx2, W2T, h2o, nullptr, 0, fo);
        temporal_v8<<<temp_blocks, 256, 0, stream>>>(h2o, hist2, Whis, WTm, fo, nullptr);
    } else {
        sage_v5<25, false><<<sage_blocks, 256, 0, stream>>>(feats, feats, idx1, W1, h1o, nullptr);
        temporal_v8<<<temp_blocks, 256, 0, stream>>>(h1o, hist1, Whis, WTm, fo, nullptr);
        sage_v5<10, true><<<sage_blocks, 256, 0, stream>>>(fo, h1o, idx2, W2, h2o, fo);
        temporal_v8<<<temp_blocks, 256, 0, stream>>>(h2o, hist2, Whis, WTm, fo, nullptr);
    }
}

// Round 10
// 156.056 us; speedup vs baseline: 2.4285x; 1.0021x over previous
//
#include <hip/hip_runtime.h>
#include <hip/hip_bf16.h>

#define N_NODES 50000
#define NUM_P   20000
#define D_DIM   128
#define ALPHA_  0.2f
#define EPS_    1e-12f
#define NT      16      // nodes per block (50000 = 3125*16, 20000 = 1250*16)

typedef __attribute__((ext_vector_type(8))) short bf16x8;
typedef __attribute__((ext_vector_type(4))) float f32x4;

__device__ __forceinline__ float4 f4zero() { return make_float4(0.f, 0.f, 0.f, 0.f); }

__device__ __forceinline__ void scale4(float4& v, const float s) {
    v.x *= s; v.y *= s; v.z *= s; v.w *= s;
}

__device__ __forceinline__ short f2bf(float f) {
    __hip_bfloat16 h = __float2bfloat16(f);
    return *reinterpret_cast<short*>(&h);
}

__device__ __forceinline__ float bf2f(short u) {
    union { unsigned i; float f; } c;
    c.i = ((unsigned)(unsigned short)u) << 16;
    return c.f;
}

__device__ __forceinline__ short4 pack4(const float4 v) {
    short4 s;
    s.x = f2bf(v.x); s.y = f2bf(v.y); s.z = f2bf(v.z); s.w = f2bf(v.w);
    return s;
}

// ---------------------------------------------------------------------------
// Weight pre-transpose+cvt to bf16:
//   o[0..32768)        = W1^T  [128 col][256 k]
//   o[32768..65536)    = W2^T  [128 col][256 k]
//   o[65536..81920)    = Whis^T[128 col][128 k]
//   o[81920..114688)   = WT^T  [128 col][256 k]
// ---------------------------------------------------------------------------
__global__ __launch_bounds__(256)
void wcvt2_kernel(const float* __restrict__ W1, const float* __restrict__ W2,
                  const float* __restrict__ Whis, const float* __restrict__ WTm,
                  short* __restrict__ o)
{
    const int i = blockIdx.x * 256 + threadIdx.x;   // 0..114687
    float v;
    if (i < 65536) {
        const float* W = (i < 32768) ? W1 : W2;
        const int t = i & 32767;
        v = W[(size_t)(t & 255) * D_DIM + (t >> 8)];
    } else if (i < 81920) {
        const int t = i - 65536;
        v = Whis[(size_t)(t & 127) * D_DIM + (t >> 7)];
    } else {
        const int t = i - 81920;
        v = WTm[(size_t)(t & 255) * D_DIM + (t >> 8)];
    }
    o[i] = f2bf(v);
}

// fp32 -> bf16 mirror (element count multiple of 1024)
__global__ __launch_bounds__(256)
void fcvt_kernel(const float* __restrict__ in, short* __restrict__ o)
{
    const int i = blockIdx.x * 256 + threadIdx.x;
    const float4 v = reinterpret_cast<const float4*>(in)[i];
    reinterpret_cast<short4*>(o)[i] = pack4(v);
}

// ---------------------------------------------------------------------------
// MFMA SAGE: src bf16 [*,128]. out0 fp32 all rows; outb bf16 rows < nb_limit;
// out1 fp32 rows >= NUM_P (feat tail).
// Gather is batch-issued: all K row-loads in flight before accumulation.
// ---------------------------------------------------------------------------
template<int K>
__global__ __launch_bounds__(256)
void sage_mfma8(const short* __restrict__ src,
                const int*   __restrict__ idx,
                const short* __restrict__ WTg,     // [128][256] bf16 = W^T
                float* __restrict__ out0,
                short* __restrict__ outb,
                int nb_limit,
                float* __restrict__ out1)
{
    __shared__ __align__(16) char uni[NT * 132 * 4];
    __shared__ float rnorm[NT];
    __shared__ int   sidx[NT * K];
    short* xs = reinterpret_cast<short*>(uni);   // [n][256] bf16, swizzled
    float* ys = reinterpret_cast<float*>(uni);   // [n][132] fp32

    const int tid  = threadIdx.x;
    const int base = blockIdx.x * NT;

    for (int i = tid; i < NT * K; i += 256)
        sidx[i] = idx[(size_t)base * K + i];
    __syncthreads();

    // ---- gather (bf16 rows, 256B): 8 groups of 32 lanes, batched loads ----
    {
        const int gp = tid >> 5;
        const int l  = tid & 31;
        for (int n = gp; n < NT; n += 8) {
            const int node = base + n;

            // preload indices (compile-time-indexed regs)
            int ridx[K];
            #pragma unroll
            for (int k = 0; k < K; ++k) ridx[k] = sidx[n * K + k];

            // issue all K+1 loads as an independent batch
            const short4 s4 = reinterpret_cast<const short4*>(src + (size_t)node * D_DIM)[l];
            short4 buf[K];
            #pragma unroll
            for (int k = 0; k < K; ++k)
                buf[k] = reinterpret_cast<const short4*>(src + (size_t)ridx[k] * D_DIM)[l];

            // accumulate
            float4 a4 = f4zero();
            #pragma unroll
            for (int k = 0; k < K; ++k) {
                a4.x += bf2f(buf[k].x); a4.y += bf2f(buf[k].y);
                a4.z += bf2f(buf[k].z); a4.w += bf2f(buf[k].w);
            }
            scale4(a4, 1.0f / (float)K);
            const int swzn = (n & 7) << 3;
            *reinterpret_cast<short4*>(&xs[n * 256 + ((l * 4) ^ swzn)])         = s4;
            *reinterpret_cast<short4*>(&xs[n * 256 + ((D_DIM + l * 4) ^ swzn)]) = pack4(a4);
        }
    }
    __syncthreads();

    // ---- MFMA: wave w -> cols [32w, 32w+32), K=256 in 8 steps ----
    const int w    = tid >> 6;
    const int l    = tid & 63;
    const int arow = l & 15;
    const int kg   = l >> 4;
    const int swz  = (arow & 7) << 3;

    f32x4 acc0 = {0.f, 0.f, 0.f, 0.f};
    f32x4 acc1 = {0.f, 0.f, 0.f, 0.f};
    const int colbase = w * 32;
    const short* b0 = WTg + (size_t)(colbase + arow) * 256 + kg * 8;
    const short* b1 = b0 + 16 * 256;

    #pragma unroll
    for (int step = 0; step < 8; ++step) {
        const int aoff = arow * 256 + ((step * 32 + kg * 8) ^ swz);
        const bf16x8 av  = *reinterpret_cast<const bf16x8*>(&xs[aoff]);
        const bf16x8 bv0 = *reinterpret_cast<const bf16x8*>(b0 + step * 32);
        const bf16x8 bv1 = *reinterpret_cast<const bf16x8*>(b1 + step * 32);
        acc0 = __builtin_amdgcn_mfma_f32_16x16x32_bf16(av, bv0, acc0, 0, 0, 0);
        acc1 = __builtin_amdgcn_mfma_f32_16x16x32_bf16(av, bv1, acc1, 0, 0, 0);
    }
    __syncthreads();

    // ---- epilogue: leaky -> ys (D layout: node=(l>>4)*4+r, col-local=l&15)
    {
        const int r0 = kg * 4;
        #pragma unroll
        for (int r = 0; r < 4; ++r) {
            float v0 = acc0[r]; v0 = v0 > 0.f ? v0 : ALPHA_ * v0;
            float v1 = acc1[r]; v1 = v1 > 0.f ? v1 : ALPHA_ * v1;
            ys[(r0 + r) * 132 + colbase + arow]      = v0;
            ys[(r0 + r) * 132 + colbase + 16 + arow] = v1;
        }
    }
    __syncthreads();

    {
        const int n  = tid >> 4;
        const int ll = tid & 15;
        float s = 0.f;
        #pragma unroll
        for (int jj = 0; jj < D_DIM; jj += 16) { const float t = ys[n * 132 + ll + jj]; s += t * t; }
        #pragma unroll
        for (int o = 8; o > 0; o >>= 1) s += __shfl_xor(s, o);
        if (ll == 0) rnorm[n] = 1.0f / fmaxf(sqrtf(s), EPS_);
    }
    __syncthreads();

    {
        const int j = tid & 127;
        const int g = tid >> 7;
        #pragma unroll
        for (int r = 0; r < 8; ++r) {
            const int n    = g * 8 + r;
            const int node = base + n;
            const float v  = ys[n * 132 + j] * rnorm[n];
            out0[(size_t)node * D_DIM + j] = v;
            if (outb != nullptr && node < nb_limit) outb[(size_t)node * D_DIM + j] = f2bf(v);
            if (out1 != nullptr && node >= NUM_P)   out1[(size_t)node * D_DIM + j] = v;
        }
    }
}

// ---------------------------------------------------------------------------
// MFMA temporal: out = l2norm(leaky([head | (mean_p hist)@Whis] @ WT)).
// head: bf16 table (rows < NUM_P). headb/outb may ALIAS (per-row read-then-
// write within the owning block only) -> no __restrict__ on them.
// ---------------------------------------------------------------------------
__global__ __launch_bounds__(256)
void temporal_mfma(const short* headb,                 // bf16 [NUM_P+,128]
                   const float* __restrict__ hist,     // [3][NUM_P][128] fp32
                   const short* __restrict__ WhisTg,   // [128][128] bf16 = Whis^T
                   const short* __restrict__ WTTg,     // [128][256] bf16 = WT^T
                   float* __restrict__ outp,           // fp32, nullable
                   short* outb)                        // bf16, nullable (may alias headb)
{
    __shared__ __align__(16) char uni[NT * 132 * 4];
    __shared__ float rnorm[NT];
    short* xs = reinterpret_cast<short*>(uni);   // [n][256] bf16 swizzled: head | hm->tf
    float* ys = reinterpret_cast<float*>(uni);   // [n][132] fp32

    const int tid  = threadIdx.x;
    const int base = blockIdx.x * NT;
    const size_t HS = (size_t)NUM_P * D_DIM;

    // ---- phase 1: head (bf16 copy) + hist mean (fp32 -> bf16), swizzled ----
    {
        const int gp = tid >> 5;
        const int l  = tid & 31;
        for (int n = gp; n < NT; n += 8) {
            const size_t off = (size_t)(base + n) * D_DIM;
            const short4 h4 = reinterpret_cast<const short4*>(headb + off)[l];
            const float4 p0 = reinterpret_cast<const float4*>(hist + off)[l];
            const float4 p1 = reinterpret_cast<const float4*>(hist + off + HS)[l];
            const float4 p2 = reinterpret_cast<const float4*>(hist + off + 2 * HS)[l];
            float4 m4;
            m4.x = (p0.x + p1.x + p2.x) * (1.0f / 3.0f);
            m4.y = (p0.y + p1.y + p2.y) * (1.0f / 3.0f);
            m4.z = (p0.z + p1.z + p2.z) * (1.0f / 3.0f);
            m4.w = (p0.w + p1.w + p2.w) * (1.0f / 3.0f);
            const int swzn = (n & 7) << 3;
            *reinterpret_cast<short4*>(&xs[n * 256 + ((l * 4) ^ swzn)])         = h4;
            *reinterpret_cast<short4*>(&xs[n * 256 + ((D_DIM + l * 4) ^ swzn)]) = pack4(m4);
        }
    }
    __syncthreads();

    const int w    = tid >> 6;
    const int l    = tid & 63;
    const int arow = l & 15;
    const int kg   = l >> 4;
    const int swz  = (arow & 7) << 3;
    const int colbase = w * 32;

    // ---- MFMA-A: tf = hm @ Whis^T (K=128, 4 steps), no activation ----
    {
        f32x4 t0 = {0.f, 0.f, 0.f, 0.f};
        f32x4 t1 = {0.f, 0.f, 0.f, 0.f};
        const short* b0 = WhisTg + (size_t)(colbase + arow) * 128 + kg * 8;
        const short* b1 = b0 + 16 * 128;
        #pragma unroll
        for (int step = 0; step < 4; ++step) {
            const int aoff = arow * 256 + ((D_DIM + step * 32 + kg * 8) ^ swz);
            const bf16x8 av  = *reinterpret_cast<const bf16x8*>(&xs[aoff]);
            const bf16x8 bv0 = *reinterpret_cast<const bf16x8*>(b0 + step * 32);
            const bf16x8 bv1 = *reinterpret_cast<const bf16x8*>(b1 + step * 32);
            t0 = __builtin_amdgcn_mfma_f32_16x16x32_bf16(av, bv0, t0, 0, 0, 0);
            t1 = __builtin_amdgcn_mfma_f32_16x16x32_bf16(av, bv1, t1, 0, 0, 0);
        }
        __syncthreads();   // all hm reads done before overwrite

        // write tf back in place of hm (bf16, swizzled A layout)
        #pragma unroll
        for (int r = 0; r < 4; ++r) {
            const int node = kg * 4 + r;
            const int swzn = (node & 7) << 3;
            xs[node * 256 + ((D_DIM + colbase + arow) ^ swzn)]      = f2bf(t0[r]);
            xs[node * 256 + ((D_DIM + colbase + 16 + arow) ^ swzn)] = f2bf(t1[r]);
        }
    }
    __syncthreads();

    // ---- MFMA-B: y = [head | tf] @ WT^T (K=256, 8 steps) ----
    f32x4 acc0 = {0.f, 0.f, 0.f, 0.f};
    f32x4 acc1 = {0.f, 0.f, 0.f, 0.f};
    {
        const short* b0 = WTTg + (size_t)(colbase + arow) * 256 + kg * 8;
        const short* b1 = b0 + 16 * 256;
        #pragma unroll
        for (int step = 0; step < 8; ++step) {
            const int aoff = arow * 256 + ((step * 32 + kg * 8) ^ swz);
            const bf16x8 av  = *reinterpret_cast<const bf16x8*>(&xs[aoff]);
            const bf16x8 bv0 = *reinterpret_cast<const bf16x8*>(b0 + step * 32);
            const bf16x8 bv1 = *reinterpret_cast<const bf16x8*>(b1 + step * 32);
            acc0 = __builtin_amdgcn_mfma_f32_16x16x32_bf16(av, bv0, acc0, 0, 0, 0);
            acc1 = __builtin_amdgcn_mfma_f32_16x16x32_bf16(av, bv1, acc1, 0, 0, 0);
        }
    }
    __syncthreads();

    // ---- epilogue: leaky -> ys ----
    {
        const int r0 = kg * 4;
        #pragma unroll
        for (int r = 0; r < 4; ++r) {
            float v0 = acc0[r]; v0 = v0 > 0.f ? v0 : ALPHA_ * v0;
            float v1 = acc1[r]; v1 = v1 > 0.f ? v1 : ALPHA_ * v1;
            ys[(r0 + r) * 132 + colbase + arow]      = v0;
            ys[(r0 + r) * 132 + colbase + 16 + arow] = v1;
        }
    }
    __syncthreads();

    {
        const int n  = tid >> 4;
        const int ll = tid & 15;
        float s = 0.f;
        #pragma unroll
        for (int jj = 0; jj < D_DIM; jj += 16) { const float t = ys[n * 132 + ll + jj]; s += t * t; }
        #pragma unroll
        for (int o = 8; o > 0; o >>= 1) s += __shfl_xor(s, o);
        if (ll == 0) rnorm[n] = 1.0f / fmaxf(sqrtf(s), EPS_);
    }
    __syncthreads();

    {
        const int j = tid & 127;
        const int g = tid >> 7;
        #pragma unroll
        for (int r = 0; r < 8; ++r) {
            const int n = g * 8 + r;
            const float v = ys[n * 132 + j] * rnorm[n];
            const size_t o = (size_t)(base + n) * D_DIM + j;
            if (outp != nullptr) outp[o] = v;
            if (outb != nullptr) outb[o] = f2bf(v);
        }
    }
}

// ---------------------------------------------------------------------------
// fp32 temporal (proven, fallback paths)
// ---------------------------------------------------------------------------
__global__ __launch_bounds__(256)
void temporal_v8(const float* __restrict__ head,
                 const float* __restrict__ hist,
                 const float* __restrict__ Whis,
                 const float* __restrict__ WTm,
                 float* __restrict__ outp,
                 short* __restrict__ outb)
{
    __shared__ float xs[NT][2 * D_DIM];
    __shared__ float hm[NT][D_DIM];
    __shared__ float rnorm[NT];

    const int tid  = threadIdx.x;
    const int base = blockIdx.x * NT;
    const size_t HS = (size_t)NUM_P * D_DIM;

    {
        const int gp = tid >> 5;
        const int l  = tid & 31;
        for (int n = gp; n < NT; n += 8) {
            const size_t off = (size_t)(base + n) * D_DIM;
            const float4 h4 = reinterpret_cast<const float4*>(head + off)[l];
            const float4 p0 = reinterpret_cast<const float4*>(hist + off)[l];
            const float4 p1 = reinterpret_cast<const float4*>(hist + off + HS)[l];
            const float4 p2 = reinterpret_cast<const float4*>(hist + off + 2 * HS)[l];
            float4 m4;
            m4.x = (p0.x + p1.x + p2.x) * (1.0f / 3.0f);
            m4.y = (p0.y + p1.y + p2.y) * (1.0f / 3.0f);
            m4.z = (p0.z + p1.z + p2.z) * (1.0f / 3.0f);
            m4.w = (p0.w + p1.w + p2.w) * (1.0f / 3.0f);
            reinterpret_cast<float4*>(&xs[n][0])[l] = h4;
            reinterpret_cast<float4*>(&hm[n][0])[l] = m4;
        }
    }
    __syncthreads();

    const int j  = tid & 127;
    const int g  = tid >> 7;
    const int nb = g * 8;

    {
        float a2[8];
        #pragma unroll
        for (int r = 0; r < 8; ++r) a2[r] = 0.f;
        for (int c4 = 0; c4 < D_DIM / 4; ++c4) {
            const int c = c4 * 4;
            const float w0 = Whis[(size_t)(c + 0) * D_DIM + j];
            const float w1 = Whis[(size_t)(c + 1) * D_DIM + j];
            const float w2 = Whis[(size_t)(c + 2) * D_DIM + j];
            const float w3 = Whis[(size_t)(c + 3) * D_DIM + j];
            #pragma unroll
            for (int r = 0; r < 8; ++r) {
                const float4 xv = *reinterpret_cast<const float4*>(&hm[nb + r][c]);
                a2[r] = fmaf(xv.w, w3, fmaf(xv.z, w2, fmaf(xv.y, w1, fmaf(xv.x, w0, a2[r]))));
            }
        }
        __syncthreads();
        #pragma unroll
        for (int r = 0; r < 8; ++r) xs[nb + r][D_DIM + j] = a2[r];
    }
    __syncthreads();

    float acc[8];
    #pragma unroll
    for (int r = 0; r < 8; ++r) acc[r] = 0.f;
    for (int c4 = 0; c4 < (2 * D_DIM) / 4; ++c4) {
        const int c = c4 * 4;
        const float w0 = WTm[(size_t)(c + 0) * D_DIM + j];
        const float w1 = WTm[(size_t)(c + 1) * D_DIM + j];
        const float w2 = WTm[(size_t)(c + 2) * D_DIM + j];
        const float w3 = WTm[(size_t)(c + 3) * D_DIM + j];
        #pragma unroll
        for (int r = 0; r < 8; ++r) {
            const float4 xv = *reinterpret_cast<const float4*>(&xs[nb + r][c]);
            acc[r] = fmaf(xv.w, w3, fmaf(xv.z, w2, fmaf(xv.y, w1, fmaf(xv.x, w0, acc[r]))));
        }
    }
    __syncthreads();

    #pragma unroll
    for (int r = 0; r < 8; ++r) {
        float v = acc[r];
        v = v > 0.f ? v : ALPHA_ * v;
        xs[nb + r][j] = v;
    }
    __syncthreads();

    {
        const int n  = tid >> 4;
        const int ll = tid & 15;
        float s = 0.f;
        #pragma unroll
        for (int jj = ll; jj < D_DIM; jj += 16) { const float t = xs[n][jj]; s += t * t; }
        #pragma unroll
        for (int o = 8; o > 0; o >>= 1) s += __shfl_xor(s, o);
        if (ll == 0) rnorm[n] = 1.0f / fmaxf(sqrtf(s), EPS_);
    }
    __syncthreads();

    #pragma unroll
    for (int r = 0; r < 8; ++r) {
        const int n = nb + r;
        const float v = xs[n][j] * rnorm[n];
        const size_t o = (size_t)(base + n) * D_DIM + j;
        if (outp != nullptr) outp[o] = v;
        if (outb != nullptr) outb[o] = f2bf(v);
    }
}

// ---------------------------------------------------------------------------
// fp32 SAGE (last-resort fallback, no workspace)
// ---------------------------------------------------------------------------
template<int K, bool SPLIT>
__global__ __launch_bounds__(256)
void sage_v5(const float* __restrict__ srcLow,
             const float* __restrict__ srcHigh,
             const int*   __restrict__ idx,
             const float* __restrict__ W,
             float* __restrict__ out0,
             float* __restrict__ out1)
{
    __shared__ float xs[NT][2 * D_DIM];
    __shared__ int   sidx[NT * K];
    __shared__ float rnorm[NT];

    const int tid  = threadIdx.x;
    const int base = blockIdx.x * NT;

    for (int i = tid; i < NT * K; i += 256)
        sidx[i] = idx[(size_t)base * K + i];
    __syncthreads();

    {
        const int gp = tid >> 5;
        const int l  = tid & 31;
        for (int n = gp; n < NT; n += 8) {
            const int node = base + n;
            const float* sp = (!SPLIT || node < NUM_P) ? srcLow : srcHigh;
            const float4 s4 = reinterpret_cast<const float4*>(sp + (size_t)node * D_DIM)[l];
            float4 a4 = f4zero();
            for (int k = 0; k < K; ++k) {
                const int r = sidx[n * K + k];
                const float* rp = (!SPLIT || r < NUM_P) ? srcLow : srcHigh;
                const float4 v4 = reinterpret_cast<const float4*>(rp + (size_t)r * D_DIM)[l];
                a4.x += v4.x; a4.y += v4.y; a4.z += v4.z; a4.w += v4.w;
            }
            scale4(a4, 1.0f / (float)K);
            reinterpret_cast<float4*>(&xs[n][0])[l]     = s4;
            reinterpret_cast<float4*>(&xs[n][D_DIM])[l] = a4;
        }
    }
    __syncthreads();

    const int j  = tid & 127;
    const int g  = tid >> 7;
    const int nb = g * 8;

    float acc[8];
    #pragma unroll
    for (int r = 0; r < 8; ++r) acc[r] = 0.f;
    for (int c4 = 0; c4 < (2 * D_DIM) / 4; ++c4) {
        const int c = c4 * 4;
        const float w0 = W[(size_t)(c + 0) * D_DIM + j];
        const float w1 = W[(size_t)(c + 1) * D_DIM + j];
        const float w2 = W[(size_t)(c + 2) * D_DIM + j];
        const float w3 = W[(size_t)(c + 3) * D_DIM + j];
        #pragma unroll
        for (int r = 0; r < 8; ++r) {
            const float4 xv = *reinterpret_cast<const float4*>(&xs[nb + r][c]);
            acc[r] = fmaf(xv.w, w3, fmaf(xv.z, w2, fmaf(xv.y, w1, fmaf(xv.x, w0, acc[r]))));
        }
    }
    __syncthreads();

    #pragma unroll
    for (int r = 0; r < 8; ++r) {
        float v = acc[r];
        v = v > 0.f ? v : ALPHA_ * v;
        xs[nb + r][j] = v;
    }
    __syncthreads();

    {
        const int n  = tid >> 4;
        const int ll = tid & 15;
        float s = 0.f;
        #pragma unroll
        for (int jj = ll; jj < D_DIM; jj += 16) { const float t = xs[n][jj]; s += t * t; }
        #pragma unroll
        for (int o = 8; o > 0; o >>= 1) s += __shfl_xor(s, o);
        if (ll == 0) rnorm[n] = 1.0f / fmaxf(sqrtf(s), EPS_);
    }
    __syncthreads();

    #pragma unroll
    for (int r = 0; r < 8; ++r) {
        const int n    = nb + r;
        const int node = base + n;
        const float v  = xs[n][j] * rnorm[n];
        out0[(size_t)node * D_DIM + j] = v;
        if (out1 != nullptr && node >= NUM_P) out1[(size_t)node * D_DIM + j] = v;
    }
}

// ---------------------------------------------------------------------------
extern "C" void kernel_launch(void* const* d_in, const int* in_sizes, int n_in,
                              void* d_out, int out_size, void* d_ws, size_t ws_size,
                              hipStream_t stream)
{
    (void)in_sizes; (void)n_in; (void)out_size;

    const float* feats = (const float*)d_in[0];
    const int*   idx1  = (const int*)  d_in[1];
    const int*   idx2  = (const int*)  d_in[2];
    const float* hist1 = (const float*)d_in[3];
    const float* hist2 = (const float*)d_in[4];
    const float* W1    = (const float*)d_in[5];
    const float* W2    = (const float*)d_in[6];
    const float* Whis  = (const float*)d_in[7];
    const float* WTm   = (const float*)d_in[8];

    float* out = (float*)d_out;
    float* h1o = out;
    float* h2o = out + (size_t)N_NODES * D_DIM;
    float* fo  = out + 2 * (size_t)N_NODES * D_DIM;

    const int sage_blocks = N_NODES / NT;  // 3125
    const int temp_blocks = NUM_P   / NT;  // 1250

    const size_t SZ_N  = (size_t)N_NODES * D_DIM;   // 6.4M elems
    const size_t SZ_P  = (size_t)NUM_P  * D_DIM;    // 2.56M elems
    const size_t WOFF  = 114688;                     // all 4 transposed weights (shorts)
    const size_t needA = (WOFF + 2 * SZ_N + SZ_P) * 2;   // ~30.9 MB
    const size_t needB = (WOFF + 2 * SZ_N) * 2;          // ~25.8 MB

    short* wsp  = (short*)d_ws;
    short* W1T  = wsp;
    short* W2T  = wsp + 32768;
    short* WhT  = wsp + 65536;
    short* WTT  = wsp + 81920;
    short* fb   = wsp + WOFF;          // bf16 feats  [N,128]
    short* hb   = fb + SZ_N;           // bf16 h1/f1  [N,128]
    short* h2b  = hb + SZ_N;           // bf16 h2     [NUM_P,128]

    if (ws_size >= needA) {
        wcvt2_kernel<<<448, 256, 0, stream>>>(W1, W2, Whis, WTm, wsp);
        fcvt_kernel<<<(int)(SZ_N / 1024), 256, 0, stream>>>(feats, fb);

        // h1: fp32 -> h1o, bf16 -> hb (all rows; sage2 gathers any row)
        sage_mfma8<25><<<sage_blocks, 256, 0, stream>>>(fb, idx1, W1T, h1o, hb, N_NODES, nullptr);
        // f1: bf16 -> hb rows [0,NUM) (reads hb as head; per-row read-then-write in-block)
        temporal_mfma<<<temp_blocks, 256, 0, stream>>>(hb, hist1, WhT, WTT, nullptr, hb);
        // h2: fp32 -> h2o, bf16 rows<NUM -> h2b, fp32 tail -> fo
        sage_mfma8<10><<<sage_blocks, 256, 0, stream>>>(hb, idx2, W2T, h2o, h2b, NUM_P, fo);
        // f2: fp32 -> fo rows [0,NUM)
        temporal_mfma<<<temp_blocks, 256, 0, stream>>>(h2b, hist2, WhT, WTT, fo, nullptr);
    } else if (ws_size >= needB) {
        wcvt2_kernel<<<448, 256, 0, stream>>>(W1, W2, Whis, WTm, wsp);
        fcvt_kernel<<<(int)(SZ_N / 1024), 256, 0, stream>>>(feats, fb);

        sage_mfma8<25><<<sage_blocks, 256, 0, stream>>>(fb, idx1, W1T, h1o, hb, N_NODES, nullptr);
        temporal_v8<<<temp_blocks, 256, 0, stream>>>(h1o, hist1, Whis, WTm, nullptr, hb);
        sage_mfma8<10><<<sage_blocks, 256, 0, stream>>>(hb, idx2, W2T, h2o, nullptr, 0, fo);
        temporal_v8<<<temp_blocks, 256, 0, stream>>>(h2o, hist2, Whis, WTm, fo, nullptr);
    } else {
        sage_v5<25, false><<<sage_blocks, 256, 0, stream>>>(feats, feats, idx1, W1, h1o, nullptr);
        temporal_v8<<<temp_blocks, 256, 0, stream>>>(h1o, hist1, Whis, WTm, fo, nullptr);
        sage_v5<10, true><<<sage_blocks, 256, 0, stream>>>(fo, h1o, idx2, W2, h2o, fo);
        temporal_v8<<<temp_blocks, 256, 0, stream>>>(h2o, hist2, Whis, WTm, fo, nullptr);
    }
}